// Round 16
// baseline (408.528 us; speedup 1.0000x reference)
//
#include <hip/hip_runtime.h>
#include <stdint.h>

typedef unsigned short u16;
typedef unsigned int u32;

#define DEVFN __device__ __forceinline__

constexpr int CB = 4;
constexpr int CT = 2048;
constexpr int CD = 1024;
constexpr int CH = 8;
constexpr int CDK = 128;
constexpr int CDV = 256;
constexpr long NROW = (long)CB * CT;   // 8192

DEVFN float b2f(u16 s){ return __uint_as_float(((u32)s) << 16); }
DEVFN u16 f2b(float f){
  u32 u = __float_as_uint(f);
  u32 r = (u + 0x7fffu + ((u >> 16) & 1u)) >> 16;
  return (u16)r;
}
DEVFN float sigm(float x){ return 1.f / (1.f + expf(-x)); }
DEVFN int swz3(int r){ return (r ^ (r >> 2)) & 3; }

// ---------------- cast X to bf16 ----------------
__global__ void cast_f32_bf16_k(const float* __restrict__ in, u16* __restrict__ out, long n4){
  long i = (long)blockIdx.x * blockDim.x + threadIdx.x;
  long stride = (long)gridDim.x * blockDim.x;
  for (; i < n4; i += stride){
    float4 v = ((const float4*)in)[i];
    ushort4 r;
    r.x = f2b(v.x); r.y = f2b(v.y); r.z = f2b(v.z); r.w = f2b(v.w);
    ((ushort4*)out)[i] = r;
  }
}

// ---------------- all weight transposes in one launch ----------------
__global__ __launch_bounds__(256) void transpose_all_k(
    const float* __restrict__ Wq, const float* __restrict__ Wk, const float* __restrict__ Wv,
    const float* __restrict__ Wg, const float* __restrict__ Wo,
    u16* __restrict__ Wqkvt, u16* __restrict__ Wgt, u16* __restrict__ Wot)
{
  int bid = blockIdx.x;
  const float* W; u16* Wt; int K, N, local;
  if (bid < 1024){ W = Wq; Wt = Wqkvt; K = 1024; N = 1024; local = bid; }
  else if (bid < 2048){ W = Wk; Wt = Wqkvt + (size_t)1024 * 1024; K = 1024; N = 1024; local = bid - 1024; }
  else if (bid < 4096){ W = Wv; Wt = Wqkvt + (size_t)2048 * 1024; K = 1024; N = 2048; local = bid - 2048; }
  else if (bid < 6144){ W = Wg; Wt = Wgt; K = 1024; N = 2048; local = bid - 4096; }
  else { W = Wo; Wt = Wot; K = 2048; N = 1024; local = bid - 6144; }
  int sh = (N == 1024) ? 5 : 6;
  int bx = local & ((1 << sh) - 1), by = local >> sh;
  int n0 = bx * 32, k0 = by * 32;

  __shared__ float tile[32][33];
  int tx = threadIdx.x & 31, ty = threadIdx.x >> 5;   // 32 x 8
  #pragma unroll
  for (int i = 0; i < 4; i++)
    tile[ty + 8*i][tx] = W[(long)(k0 + ty + 8*i) * N + n0 + tx];
  __syncthreads();
  #pragma unroll
  for (int i = 0; i < 4; i++){
    int nn = ty + 8*i;
    Wt[(long)(n0 + nn) * K + k0 + tx] = f2b(tile[tx][nn]);
  }
}

typedef __bf16 bf16x8 __attribute__((ext_vector_type(8)));
typedef float f32x4 __attribute__((ext_vector_type(4)));

DEVFN void store_c(float* p, float v){ *p = v; }
DEVFN void store_c(u16* p, float v){ *p = f2b(v); }

DEVFN void gload16(const void* g, void* l){
  __builtin_amdgcn_global_load_lds((__attribute__((address_space(1))) void*)g,
                                   (__attribute__((address_space(3))) void*)l, 16, 0, 0);
}

// ======== 128x128 MFMA GEMM (NT), 4 waves, BK=64, single-buffered (m97 structure) ========
// 32KB LDS -> ~5 blocks/CU; cross-block wave overlap hides the per-tile vmcnt(0) drain
// (measured ladder: this structure = 874-912 TF at 128^2 vs 737 TF for the 64KB dbuf variant).
template <typename OutT>
__global__ __launch_bounds__(256) void gemm128_k(
    const u16* __restrict__ A, const u16* __restrict__ Bt, OutT* __restrict__ C,
    int M, int N, int K)
{
  __shared__ u16 As[128 * 64];
  __shared__ u16 Bs[128 * 64];
  int tid = threadIdx.x;
  int lane = tid & 63, wv = tid >> 6;
  int wm = wv & 1, wn = wv >> 1;          // 2 (M) x 2 (N); wave tile 64x64
  int l15 = lane & 15, lhi = lane >> 4;
  int m0 = blockIdx.y * 128, n0 = blockIdx.x * 128;
  const u16* Ab = A + (long)m0 * K;
  const u16* Bb = Bt + (long)n0 * K;

  f32x4 acc[4][4] = {};

  int T = K >> 6;
  for (int t = 0; t < T; t++){
    int k0 = t * 64;
    #pragma unroll
    for (int p = 0; p < 4; p++){
      int X = p * 256 + tid;              // 0..1023 (128 rows x 8 slots)
      int r = X >> 3, jj = X & 7;
      gload16(Ab + (long)r * K + k0 + ((jj ^ (r & 7)) * 8), &As[(size_t)X * 8]);
    }
    #pragma unroll
    for (int p = 0; p < 4; p++){
      int X = p * 256 + tid;
      int r = X >> 3, jj = X & 7;
      gload16(Bb + (long)r * K + k0 + ((jj ^ (r & 7)) * 8), &Bs[(size_t)X * 8]);
    }
    asm volatile("s_waitcnt vmcnt(0)" ::: "memory");
    __builtin_amdgcn_s_barrier();

    #pragma unroll
    for (int kk = 0; kk < 64; kk += 32){
      int s = (kk >> 3) + lhi;
      bf16x8 av[4], bv[4];
      #pragma unroll
      for (int m = 0; m < 4; m++){
        int r = wm * 64 + m * 16 + l15;
        av[m] = *(const bf16x8*)&As[r * 64 + ((s ^ (r & 7)) * 8)];
      }
      #pragma unroll
      for (int n = 0; n < 4; n++){
        int r = wn * 64 + n * 16 + l15;
        bv[n] = *(const bf16x8*)&Bs[r * 64 + ((s ^ (r & 7)) * 8)];
      }
      #pragma unroll
      for (int m = 0; m < 4; m++)
        #pragma unroll
        for (int n = 0; n < 4; n++)
          acc[m][n] = __builtin_amdgcn_mfma_f32_16x16x32_bf16(av[m], bv[n], acc[m][n], 0, 0, 0);
    }
    asm volatile("s_waitcnt lgkmcnt(0)" ::: "memory");
    __builtin_amdgcn_s_barrier();        // all reads done before next stage overwrites
  }

  #pragma unroll
  for (int m = 0; m < 4; m++)
    #pragma unroll
    for (int n = 0; n < 4; n++)
      #pragma unroll
      for (int j = 0; j < 4; j++){
        long row = m0 + wm * 64 + m * 16 + lhi * 4 + j;
        long col = n0 + wn * 64 + n * 16 + l15;
        store_c(&C[row * (long)N + col], acc[m][n][j]);
      }
}

// ---------------- Wab pack ----------------
__global__ __launch_bounds__(256) void build_wab_k(
    const float* __restrict__ Wa, const float* __restrict__ Wb, u16* __restrict__ Wab)
{
  int idx = blockIdx.x * 256 + threadIdx.x;
  int c = idx >> 10, k = idx & 1023;
  float v = (c < 8) ? Wa[k * 8 + c] : Wb[k * 8 + (c - 8)];
  Wab[c * 1024 + k] = f2b(v);
}

// ---------------- alpha/beta via MFMA ----------------
__global__ __launch_bounds__(256) void ab_mfma_k(
    const u16* __restrict__ Xb, const u16* __restrict__ Wab,
    const float* __restrict__ A_log, const float* __restrict__ dt_bias,
    float* __restrict__ alpha, float* __restrict__ beta)
{
  __shared__ u16 Ws[16 * 1024];
  int tid = threadIdx.x, lane = tid & 63, wv = tid >> 6;
  #pragma unroll
  for (int p = 0; p < 8; p++){
    int X = p * 256 + tid;
    int r = X >> 7, s = X & 127;
    gload16(Wab + r * 1024 + (s ^ (r & 7)) * 8, &Ws[(size_t)X * 8]);
  }
  int l15 = lane & 15, lhi = lane >> 4;
  int row0 = blockIdx.x * 64 + wv * 16;
  const u16* Arow = Xb + (long)(row0 + l15) * 1024 + lhi * 8;
  __syncthreads();

  f32x4 acc = {0.f, 0.f, 0.f, 0.f};
  #pragma unroll 8
  for (int ks = 0; ks < 32; ks++){
    bf16x8 av = *(const bf16x8*)(Arow + ks * 32);
    int slot = ks * 4 + lhi;
    bf16x8 bv = *(const bf16x8*)&Ws[l15 * 1024 + (slot ^ (l15 & 7)) * 8];
    acc = __builtin_amdgcn_mfma_f32_16x16x32_bf16(av, bv, acc, 0, 0, 0);
  }

  int col = l15;
  float nA = 0.f, db = 0.f;
  if (col < 8){ nA = -expf(A_log[col]); db = dt_bias[col]; }
  #pragma unroll
  for (int j = 0; j < 4; j++){
    long row = row0 + lhi * 4 + j;
    float v = acc[j];
    if (col < 8){
      float xv = v + db;
      float sp = fmaxf(xv, 0.f) + log1pf(expf(-fabsf(xv)));
      alpha[row * 8 + col] = expf(nA * sp);
    } else {
      beta[row * 8 + (col - 8)] = sigm(v);
    }
  }
}

// ---------------- causal depthwise conv + SiLU (+ head L2 norm) ----------------
template<int DH, bool NORM>
__global__ __launch_bounds__(DH/2) void conv_silu8_k(
    const u16* __restrict__ pre, int cstride, const float* __restrict__ cw,
    const float* __restrict__ cb, u16* __restrict__ out)
{
  int idx = blockIdx.x;
  int h = idx & 7;
  int tg = (idx >> 3) & 255;          // CT/8 = 256 groups
  int b = idx >> 11;
  int t0 = tg * 8;
  int tidx = threadIdx.x;
  int c2 = tidx * 2;
  int ch = h * DH + c2;
  const u16* base = pre + ((long)b * CT) * cstride + ch;
  float w0a = cw[ch * 4 + 0], w0b = cw[ch * 4 + 1], w0c = cw[ch * 4 + 2], w0d = cw[ch * 4 + 3];
  float w1a = cw[(ch + 1) * 4 + 0], w1b = cw[(ch + 1) * 4 + 1], w1c = cw[(ch + 1) * 4 + 2], w1d = cw[(ch + 1) * 4 + 3];
  float bs0 = cb[ch], bs1 = cb[ch + 1];

  u32 rr[11];
  #pragma unroll
  for (int i = 0; i < 11; i++){
    int t = t0 - 3 + i;
    rr[i] = (t >= 0) ? *(const u32*)(base + (long)t * cstride) : 0u;
  }
  #pragma unroll
  for (int tt = 0; tt < 8; tt++){
    int t = t0 + tt;
    float x0a = b2f((u16)(rr[tt] & 0xffffu)),     x1a = b2f((u16)(rr[tt] >> 16));
    float x0b = b2f((u16)(rr[tt + 1] & 0xffffu)), x1b = b2f((u16)(rr[tt + 1] >> 16));
    float x0c = b2f((u16)(rr[tt + 2] & 0xffffu)), x1c = b2f((u16)(rr[tt + 2] >> 16));
    float x0d = b2f((u16)(rr[tt + 3] & 0xffffu)), x1d = b2f((u16)(rr[tt + 3] >> 16));
    float a0 = fmaf(w0a, x0a, fmaf(w0b, x0b, fmaf(w0c, x0c, fmaf(w0d, x0d, bs0))));
    float a1 = fmaf(w1a, x1a, fmaf(w1b, x1b, fmaf(w1c, x1c, fmaf(w1d, x1d, bs1))));
    float y0 = a0 * sigm(a0), y1 = a1 * sigm(a1);
    if (NORM){
      float ss = y0 * y0 + y1 * y1;
      #pragma unroll
      for (int off = 1; off < 64; off <<= 1) ss += __shfl_xor(ss, off);
      float inv = 1.f / fmaxf(sqrtf(ss), 1e-12f);
      y0 *= inv; y1 *= inv;
    }
    u32 r = (u32)f2b(y0) | ((u32)f2b(y1) << 16);
    *(u32*)(out + (((long)b * CT + t) * 8 + h) * DH + c2) = r;
  }
}

// ============ chunked delta rule: per-chunk metadata (L=32) ============
__global__ __launch_bounds__(256) void chunk_meta_k(
    const u16* __restrict__ qn, const u16* __restrict__ kn, const u16* __restrict__ vn,
    const float* __restrict__ alpha, const float* __restrict__ beta,
    u16* __restrict__ TGK_g, u16* __restrict__ TVT_g, u16* __restrict__ P_g,
    u16* __restrict__ KTS_g, float* __restrict__ scal_g)
{
  int bid = blockIdx.x;
  int c = bid & 63, bh = bid >> 6;
  int b = bh >> 3, h = bh & 7;
  long rowb = (long)b * CT + c * 32;
  int tid = threadIdx.x, lane = tid & 63, wv = tid >> 6;
  int l15 = lane & 15, lhi = lane >> 4;
  int mt = wv & 1, nt = wv >> 1;

  __shared__ u16 Kc[4096], Qc[4096], Vl[8192];
  __shared__ u16 Vt[10240];    // [v 256][s 32] stride 40
  __shared__ u16 KTG[5120];    // [k 128][s 32] stride 40
  __shared__ u16 TinvL[1280];  // [s 32][s' 32] stride 40
  __shared__ float Al[32 * 33];
  __shared__ float al_s[32], be_s[32], cums[33], bscal[32], gsl[32];

  #pragma unroll
  for (int p = 0; p < 2; p++){
    int X = p * 256 + tid; int r = X >> 4, jj = X & 15;
    gload16(kn + ((rowb + r) * 8 + h) * 128 + (jj ^ (r & 7)) * 8, &Kc[(size_t)X * 8]);
  }
  #pragma unroll
  for (int p = 0; p < 2; p++){
    int X = p * 256 + tid; int r = X >> 4, jj = X & 15;
    gload16(qn + ((rowb + r) * 8 + h) * 128 + (jj ^ (r & 7)) * 8, &Qc[(size_t)X * 8]);
  }
  #pragma unroll
  for (int p = 0; p < 4; p++){
    int X = p * 256 + tid; int r = X >> 5, cc = X & 31;
    gload16(vn + ((rowb + r) * 8 + h) * 256 + cc * 8, &Vl[(size_t)X * 8]);
  }
  if (tid < 32) al_s[tid] = alpha[(rowb + tid) * 8 + h];
  else if (tid < 64) be_s[tid - 32] = beta[(rowb + tid - 32) * 8 + h];
  __syncthreads();
  if (tid == 0){
    float cacc = 0.f; cums[0] = 0.f;
    for (int j = 0; j < 32; j++){ cacc += logf(al_s[j]); cums[j + 1] = cacc; }
  }
  __syncthreads();
  if (tid < 32){
    bscal[tid] = be_s[tid] * expf(cums[32] - cums[tid + 1]);
    gsl[tid] = expf(cums[tid]);
  }
  asm volatile("s_waitcnt vmcnt(0)" ::: "memory");
  __syncthreads();

  #pragma unroll
  for (int i = 0; i < 16; i++){
    u32 lo = Vl[(2 * i) * 256 + tid];
    u32 hi = Vl[(2 * i + 1) * 256 + tid];
    *(u32*)&Vt[tid * 40 + 2 * i] = lo | (hi << 16);
  }

  f32x4 rk = {0.f,0.f,0.f,0.f}, rq = {0.f,0.f,0.f,0.f};
  int ra = mt * 16 + l15, rb = nt * 16 + l15;
  #pragma unroll
  for (int ks = 0; ks < 4; ks++){
    int slot = ks * 4 + lhi;
    bf16x8 ak = *(const bf16x8*)&Kc[ra * 128 + (slot ^ (ra & 7)) * 8];
    bf16x8 aq = *(const bf16x8*)&Qc[ra * 128 + (slot ^ (ra & 7)) * 8];
    bf16x8 bk = *(const bf16x8*)&Kc[rb * 128 + (slot ^ (rb & 7)) * 8];
    rk = __builtin_amdgcn_mfma_f32_16x16x32_bf16(ak, bk, rk, 0, 0, 0);
    rq = __builtin_amdgcn_mfma_f32_16x16x32_bf16(aq, bk, rq, 0, 0, 0);
  }
  int s_ = nt * 16 + l15;
  long pb_ = (long)bid * 1024;
  #pragma unroll
  for (int j = 0; j < 4; j++){
    int i_ = mt * 16 + lhi * 4 + j;
    float e = (s_ < i_) ? expf(cums[i_] - cums[s_ + 1]) * be_s[s_] : 0.f;
    Al[i_ * 33 + s_] = rk[j] * e;
    P_g[pb_ + i_ * 32 + s_] = f2b(rq[j] * e);
  }
  __syncthreads();

  if (tid < 32){
    float x[32];
    #pragma unroll
    for (int i = 0; i < 32; i++) x[i] = (i == tid) ? 1.f : 0.f;
    #pragma unroll
    for (int s = 0; s < 31; s++){
      float xs = x[s];
      #pragma unroll
      for (int i = s + 1; i < 32; i++) x[i] = fmaf(-Al[i * 33 + s], xs, x[i]);
    }
    #pragma unroll
    for (int i = 0; i < 32; i++) TinvL[i * 40 + tid] = f2b(x[i]);
    scal_g[(long)bid * 48 + tid] = gsl[tid];
    if (tid == 0) scal_g[(long)bid * 48 + 32] = expf(cums[32]);
  } else if (tid >= 64){
    int t0 = tid - 64;
    #pragma unroll
    for (int e2 = 0; e2 < 22; e2++){
      int e = t0 + e2 * 192;
      if (e < 4096){
        int k = e >> 5, s2 = e & 31;
        int slot = k >> 3;
        float kv = b2f(Kc[s2 * 128 + (slot ^ (s2 & 7)) * 8 + (k & 7)]);
        KTS_g[(long)bid * 4096 + k * 32 + s2] = f2b(kv * bscal[s2]);
        KTG[k * 40 + s2] = f2b(kv * gsl[s2]);
      }
    }
  }
  __syncthreads();

  long tb = (long)bid * 4096;
  #pragma unroll
  for (int p = 0; p < 4; p++){
    int idx = wv * 4 + p; int ts = idx >> 3, tk = idx & 7;
    bf16x8 aT = *(const bf16x8*)&TinvL[(ts * 16 + l15) * 40 + lhi * 8];
    bf16x8 bK2 = *(const bf16x8*)&KTG[(tk * 16 + l15) * 40 + lhi * 8];
    f32x4 z = {0.f,0.f,0.f,0.f};
    f32x4 d = __builtin_amdgcn_mfma_f32_16x16x32_bf16(aT, bK2, z, 0, 0, 0);
    #pragma unroll
    for (int j = 0; j < 4; j++)
      TGK_g[tb + (ts * 16 + lhi * 4 + j) * 128 + tk * 16 + l15] = f2b(d[j]);
  }
  long vb = (long)bid * 8192;
  #pragma unroll
  for (int p = 0; p < 8; p++){
    int idx = wv * 8 + p; int tv = idx >> 1, ts2 = idx & 1;
    bf16x8 aV = *(const bf16x8*)&Vt[(tv * 16 + l15) * 40 + lhi * 8];
    bf16x8 bT2 = *(const bf16x8*)&TinvL[(ts2 * 16 + l15) * 40 + lhi * 8];
    f32x4 z = {0.f,0.f,0.f,0.f};
    f32x4 d = __builtin_amdgcn_mfma_f32_16x16x32_bf16(aV, bT2, z, 0, 0, 0);
    #pragma unroll
    for (int j = 0; j < 4; j++)
      TVT_g[vb + (tv * 16 + lhi * 4 + j) * 32 + ts2 * 16 + l15] = f2b(d[j]);
  }
}

// ============ chunked delta rule: main scan — EXACT R10 structure (proven) ============
__global__ __launch_bounds__(256) void chunk_scan_k(
    const u16* __restrict__ qn, const u16* __restrict__ TGK_g, const u16* __restrict__ TVT_g,
    const u16* __restrict__ P_g, const u16* __restrict__ KTS_g,
    const float* __restrict__ scal_g, const float* __restrict__ prev,
    u16* __restrict__ obuf, float* __restrict__ fstate)
{
  int bid = blockIdx.x;
  int bh = bid & 31, vs = bid >> 5;
  int b = bh >> 3, h = bh & 7;
  int tid = threadIdx.x, lane = tid & 63, wv = tid >> 6;
  int l15 = lane & 15, lhi = lane >> 4;
  int mv = wv & 1, nn = wv >> 1;

  __shared__ u16 TG[2][4096];
  __shared__ u16 Qc[2][4096];
  __shared__ u16 TVs[2][1024];
  __shared__ float scal[2][48];
  __shared__ u16 KT[2][4096];
  __shared__ u16 Ps[2][1024];
  __shared__ u16 Sb[32 * 136];
  __shared__ u16 Ub[32 * 40];

  auto issue_g1 = [&](int c, int bf){   // 8 loads/wave
    long cb_ = (long)bh * 64 + c;
    const u16* Tb_ = TGK_g + cb_ * 4096;
    #pragma unroll
    for (int p = 0; p < 2; p++){
      int X = p * 256 + tid; int r = X >> 4, jj = X & 15;
      gload16(Tb_ + r * 128 + (jj ^ (r & 7)) * 8, &TG[bf][(size_t)X * 8]);
    }
    long rowb = (long)b * CT + c * 32;
    #pragma unroll
    for (int p = 0; p < 2; p++){
      int X = p * 256 + tid; int r = X >> 4, jj = X & 15;
      gload16(qn + ((rowb + r) * 8 + h) * 128 + (jj ^ (r & 7)) * 8, &Qc[bf][(size_t)X * 8]);
    }
    if (lane < 32){
      int X = wv * 32 + lane; int r = X >> 2, jj = X & 3;
      gload16(TVT_g + cb_ * 8192 + (vs * 32 + r) * 32 + (jj ^ swz3(r)) * 8, &TVs[bf][(size_t)X * 8]);
    }
    long sbase = cb_ * 48;
    #pragma unroll
    for (int p = 0; p < 3; p++){
      int X = wv * 3 + p;
      if (lane == 0) gload16(scal_g + sbase + X * 4, &scal[bf][X * 4]);
    }
  };
  auto issue_g2 = [&](int c, int bf){   // 3 loads/wave
    long cb_ = (long)bh * 64 + c;
    const u16* Kb_ = KTS_g + cb_ * 4096;
    #pragma unroll
    for (int p = 0; p < 2; p++){
      int X = p * 256 + tid; int r = X >> 2, jj = X & 3;
      gload16(Kb_ + (r * 4 + (jj ^ swz3(r))) * 8, &KT[bf][(size_t)X * 8]);
    }
    if (lane < 32){
      int X = wv * 32 + lane; int r = X >> 2, jj = X & 3;
      gload16(P_g + cb_ * 1024 + (r * 4 + (jj ^ swz3(r))) * 8, &Ps[bf][(size_t)X * 8]);
    }
  };

  // ---- prologue: g1(0) then g2(0); prev state -> regs + Sb
  issue_g1(0, 0);
  issue_g2(0, 0);
  f32x4 st[4];
  {
    const float* pbv = prev + ((long)bh * 128) * 256 + vs * 32;
    #pragma unroll
    for (int tt = 0; tt < 4; tt++){
      int k = (nn * 4 + tt) * 16 + l15;
      #pragma unroll
      for (int j = 0; j < 4; j++){
        int v = mv * 16 + lhi * 4 + j;
        st[tt][j] = pbv[(long)k * 256 + v];
      }
    }
  }
  #pragma unroll
  for (int tt = 0; tt < 4; tt++){
    int k = (nn * 4 + tt) * 16 + l15;
    #pragma unroll
    for (int j = 0; j < 4; j++){
      int v = mv * 16 + lhi * 4 + j;
      Sb[v * 136 + k] = f2b(st[tt][j]);
    }
  }
  asm volatile("s_waitcnt vmcnt(3) lgkmcnt(0)" ::: "memory");
  __builtin_amdgcn_s_barrier();

  int rv = mv * 16 + l15, ri = nn * 16 + l15;
  for (int c = 0; c < 64; ++c){
    int bf = c & 1;
    // ---- Phase A: Us = TGK@S, o1 = Q@S; U = TVT - Us -> Ub
    f32x4 us = {0.f,0.f,0.f,0.f}, o1 = {0.f,0.f,0.f,0.f};
    #pragma unroll
    for (int ks = 0; ks < 4; ks++){
      bf16x8 aS = *(const bf16x8*)&Sb[rv * 136 + ks * 32 + lhi * 8];
      int slot = ks * 4 + lhi;
      bf16x8 bT = *(const bf16x8*)&TG[bf][ri * 128 + (slot ^ (ri & 7)) * 8];
      bf16x8 bQ = *(const bf16x8*)&Qc[bf][ri * 128 + (slot ^ (ri & 7)) * 8];
      us = __builtin_amdgcn_mfma_f32_16x16x32_bf16(aS, bT, us, 0, 0, 0);
      o1 = __builtin_amdgcn_mfma_f32_16x16x32_bf16(aS, bQ, o1, 0, 0, 0);
    }
    if (c + 1 < 64) issue_g1(c + 1, bf ^ 1);
    #pragma unroll
    for (int j = 0; j < 4; j++){
      int v = mv * 16 + lhi * 4 + j;
      float tv = b2f(TVs[bf][v * 32 + ((ri >> 3) ^ swz3(v)) * 8 + (ri & 7)]);
      Ub[v * 40 + ri] = f2b(tv - us[j]);
    }
    asm volatile("s_waitcnt lgkmcnt(0)" ::: "memory");
    if (c + 1 < 64) asm volatile("s_waitcnt vmcnt(8)" ::: "memory");
    else            asm volatile("s_waitcnt vmcnt(0)" ::: "memory");
    __builtin_amdgcn_s_barrier();

    // ---- Phase B: O = U@P^T + gi*o1 ; S' = Gt*S + U@KTS^T
    float Gt = scal[bf][32];
    f32x4 oacc;
    {
      bf16x8 aU = *(const bf16x8*)&Ub[rv * 40 + lhi * 8];
      bf16x8 bP = *(const bf16x8*)&Ps[bf][ri * 32 + (lhi ^ swz3(ri)) * 8];
      f32x4 z = {0.f,0.f,0.f,0.f};
      oacc = __builtin_amdgcn_mfma_f32_16x16x32_bf16(aU, bP, z, 0, 0, 0);
      #pragma unroll
      for (int tt = 0; tt < 4; tt++){
        int rk_ = (nn * 4 + tt) * 16 + l15;
        bf16x8 bK = *(const bf16x8*)&KT[bf][rk_ * 32 + (lhi ^ swz3(rk_)) * 8];
        f32x4 ci = st[tt] * Gt;
        st[tt] = __builtin_amdgcn_mfma_f32_16x16x32_bf16(aU, bK, ci, 0, 0, 0);
      }
    }
    {
      float gi = scal[bf][ri];
      ushort4 pk;
      pk.x = f2b(oacc[0] + gi * o1[0]);
      pk.y = f2b(oacc[1] + gi * o1[1]);
      pk.z = f2b(oacc[2] + gi * o1[2]);
      pk.w = f2b(oacc[3] + gi * o1[3]);
      *(ushort4*)&obuf[(((long)bh * CT) + c * 32 + ri) * 256 + vs * 32 + mv * 16 + lhi * 4] = pk;
    }
    if (c + 1 < 64) issue_g2(c + 1, bf ^ 1);
    #pragma unroll
    for (int tt = 0; tt < 4; tt++){
      int k = (nn * 4 + tt) * 16 + l15;
      #pragma unroll
      for (int j = 0; j < 4; j++){
        int v = mv * 16 + lhi * 4 + j;
        Sb[v * 136 + k] = f2b(st[tt][j]);
      }
    }
    asm volatile("s_waitcnt lgkmcnt(0)" ::: "memory");
    if (c + 1 < 64) asm volatile("s_waitcnt vmcnt(3)" ::: "memory");
    else            asm volatile("s_waitcnt vmcnt(0)" ::: "memory");
    __builtin_amdgcn_s_barrier();
  }

  // ---- epilogue: final state
  {
    float* fb = fstate + ((long)bh * 128) * 256 + vs * 32;
    #pragma unroll
    for (int tt = 0; tt < 4; tt++){
      int k = (nn * 4 + tt) * 16 + l15;
      #pragma unroll
      for (int j = 0; j < 4; j++){
        int v = mv * 16 + lhi * 4 + j;
        fb[(long)k * 256 + v] = st[tt][j];
      }
    }
  }
}

// ---------------- gated RMSNorm: one wave per (b,t,h) ----------------
__global__ __launch_bounds__(256) void rms_gate_k(
    const u16* __restrict__ o, const u16* __restrict__ gate,
    const float* __restrict__ nw, u16* __restrict__ ofin)
{
  long idx = (long)blockIdx.x * 4 + (threadIdx.x >> 6);
  int lane = threadIdx.x & 63;
  int h = (int)(idx & 7);
  long bt = idx >> 3;
  int b = (int)(bt >> 11);
  long t = bt & (CT - 1);
  long obase = (((long)(b * 8 + h)) * CT + t) * CDV + lane * 4;
  long base = idx * CDV + lane * 4;
  ushort4 o4 = *(const ushort4*)(o + obase);
  float ox = b2f(o4.x), oy = b2f(o4.y), oz = b2f(o4.z), ow = b2f(o4.w);
  float ss = ox*ox + oy*oy + oz*oz + ow*ow;
  #pragma unroll
  for (int off = 1; off < 64; off <<= 1) ss += __shfl_xor(ss, off);
  float r = rsqrtf(ss * (1.f / CDV) + 1e-5f);
  ushort4 g4 = *(const ushort4*)(gate + base);
  float w0 = nw[lane*4], w1 = nw[lane*4+1], w2 = nw[lane*4+2], w3 = nw[lane*4+3];
  ushort4 res;
  res.x = f2b(ox * r * w0 * sigm(b2f(g4.x)));
  res.y = f2b(oy * r * w1 * sigm(b2f(g4.y)));
  res.z = f2b(oz * r * w2 * sigm(b2f(g4.z)));
  res.w = f2b(ow * r * w3 * sigm(b2f(g4.w)));
  *(ushort4*)(ofin + base) = res;
}

// ---------------- host launch ----------------
extern "C" void kernel_launch(void* const* d_in, const int* in_sizes, int n_in,
                              void* d_out, int out_size, void* d_ws, size_t ws_size,
                              hipStream_t stream)
{
  (void)in_sizes; (void)n_in; (void)out_size; (void)ws_size;
  const float* X    = (const float*)d_in[0];
  const float* prev = (const float*)d_in[1];
  const float* Wq   = (const float*)d_in[2];
  const float* Wk   = (const float*)d_in[3];
  const float* Wv   = (const float*)d_in[4];
  const float* Wa   = (const float*)d_in[5];
  const float* Wb   = (const float*)d_in[6];
  const float* Wg   = (const float*)d_in[7];
  const float* Wo   = (const float*)d_in[8];
  const float* qcw  = (const float*)d_in[9];
  const float* qcb  = (const float*)d_in[10];
  const float* kcw  = (const float*)d_in[11];
  const float* kcb  = (const float*)d_in[12];
  const float* vcw  = (const float*)d_in[13];
  const float* vcb  = (const float*)d_in[14];
  const float* onw  = (const float*)d_in[15];
  const float* Alog = (const float*)d_in[16];
  const float* dtb  = (const float*)d_in[17];

  float* out = (float*)d_out;
  float* fstate = out + (long)CB * CT * CD;

  char* ws = (char*)d_ws;
  size_t off = 0;
  auto alloc = [&](size_t bytes) -> char* {
    char* p = ws + off;
    off += (bytes + 255) & ~(size_t)255;
    return p;
  };
  u16* Xb     = (u16*)alloc(NROW * CD * 2);
  u16* Wqkvt  = (u16*)alloc((size_t)4096 * 1024 * 2);
  u16* Wgt    = (u16*)alloc((size_t)2048 * 1024 * 2);
  u16* Wot    = (u16*)alloc((size_t)1024 * 2048 * 2);
  u16* qkvpre = (u16*)alloc(NROW * 4096 * 2);
  u16* gpre   = (u16*)alloc(NROW * 2048 * 2);
  float* alpha = (float*)alloc(NROW * 8 * 4);
  float* beta  = (float*)alloc(NROW * 8 * 4);
  u16* qn   = (u16*)alloc(NROW * 1024 * 2);
  u16* kn   = (u16*)alloc(NROW * 1024 * 2);
  u16* vn   = (u16*)alloc(NROW * 2048 * 2);
  u16* ofin = (u16*)alloc(NROW * 2048 * 2);
  u16* Wab  = (u16*)alloc((size_t)16 * 1024 * 2);
  // aliases (lifetime-checked):
  // TGK -> Xb (EXACT); TVT -> ofin (EXACT); qkvpre partition:
  //   obuf [0..16,777,216) | P [16,777,216..18,874,368) | scal [18,874,368..19,070,976)
  //   KTS [19,136,512..27,525,120).  Wot never aliased.
  u16* TGK_g  = Xb;
  u16* TVT_g  = ofin;
  u16* obuf   = qkvpre;
  u16* P_g    = qkvpre + (size_t)16777216;
  float* scal_g = (float*)(qkvpre + (size_t)18874368);
  u16* KTS_g  = qkvpre + (size_t)19136512;

  cast_f32_bf16_k<<<2048, 256, 0, stream>>>(X, Xb, NROW * CD / 4);
  build_wab_k<<<64, 256, 0, stream>>>(Wa, Wb, Wab);
  transpose_all_k<<<8192, 256, 0, stream>>>(Wq, Wk, Wv, Wg, Wo, Wqkvt, Wgt, Wot);

  gemm128_k<u16><<<dim3(32, 64), 256, 0, stream>>>(Xb, Wqkvt, qkvpre, 8192, 4096, 1024);
  gemm128_k<u16><<<dim3(16, 64), 256, 0, stream>>>(Xb, Wgt, gpre, 8192, 2048, 1024);
  ab_mfma_k<<<128, 256, 0, stream>>>(Xb, Wab, Alog, dtb, alpha, beta);

  conv_silu8_k<128, true><<<CB * (CT / 8) * CH, 64, 0, stream>>>(qkvpre, 4096, qcw, qcb, qn);
  conv_silu8_k<128, true><<<CB * (CT / 8) * CH, 64, 0, stream>>>(qkvpre + 1024, 4096, kcw, kcb, kn);
  conv_silu8_k<256, false><<<CB * (CT / 8) * CH, 128, 0, stream>>>(qkvpre + 2048, 4096, vcw, vcb, vn);

  chunk_meta_k<<<2048, 256, 0, stream>>>(qn, kn, vn, alpha, beta,
                                         TGK_g, TVT_g, P_g, KTS_g, scal_g);
  chunk_scan_k<<<256, 256, 0, stream>>>(qn, TGK_g, TVT_g, P_g, KTS_g, scal_g,
                                        prev, obuf, fstate);

  rms_gate_k<<<CB * CT * CH / 4, 256, 0, stream>>>(obuf, gpre, onw, ofin);
  gemm128_k<float><<<dim3(8, 64), 256, 0, stream>>>(ofin, Wot, out, 8192, 1024, 2048);
}

// Round 17
// 385.862 us; speedup vs baseline: 1.0587x; 1.0587x over previous
//
#include <hip/hip_runtime.h>
#include <stdint.h>

typedef unsigned short u16;
typedef unsigned int u32;

#define DEVFN __device__ __forceinline__

constexpr int CB = 4;
constexpr int CT = 2048;
constexpr int CD = 1024;
constexpr int CH = 8;
constexpr int CDK = 128;
constexpr int CDV = 256;
constexpr long NROW = (long)CB * CT;   // 8192

DEVFN float b2f(u16 s){ return __uint_as_float(((u32)s) << 16); }
DEVFN u16 f2b(float f){
  u32 u = __float_as_uint(f);
  u32 r = (u + 0x7fffu + ((u >> 16) & 1u)) >> 16;
  return (u16)r;
}
DEVFN float sigm(float x){ return 1.f / (1.f + expf(-x)); }
DEVFN int swz3(int r){ return (r ^ (r >> 2)) & 3; }

// ---------------- cast X to bf16 ----------------
__global__ void cast_f32_bf16_k(const float* __restrict__ in, u16* __restrict__ out, long n4){
  long i = (long)blockIdx.x * blockDim.x + threadIdx.x;
  long stride = (long)gridDim.x * blockDim.x;
  for (; i < n4; i += stride){
    float4 v = ((const float4*)in)[i];
    ushort4 r;
    r.x = f2b(v.x); r.y = f2b(v.y); r.z = f2b(v.z); r.w = f2b(v.w);
    ((ushort4*)out)[i] = r;
  }
}

// ---------------- all weight transposes in one launch ----------------
__global__ __launch_bounds__(256) void transpose_all_k(
    const float* __restrict__ Wq, const float* __restrict__ Wk, const float* __restrict__ Wv,
    const float* __restrict__ Wg, const float* __restrict__ Wo,
    u16* __restrict__ Wqkvt, u16* __restrict__ Wgt, u16* __restrict__ Wot)
{
  int bid = blockIdx.x;
  const float* W; u16* Wt; int K, N, local;
  if (bid < 1024){ W = Wq; Wt = Wqkvt; K = 1024; N = 1024; local = bid; }
  else if (bid < 2048){ W = Wk; Wt = Wqkvt + (size_t)1024 * 1024; K = 1024; N = 1024; local = bid - 1024; }
  else if (bid < 4096){ W = Wv; Wt = Wqkvt + (size_t)2048 * 1024; K = 1024; N = 2048; local = bid - 2048; }
  else if (bid < 6144){ W = Wg; Wt = Wgt; K = 1024; N = 2048; local = bid - 4096; }
  else { W = Wo; Wt = Wot; K = 2048; N = 1024; local = bid - 6144; }
  int sh = (N == 1024) ? 5 : 6;
  int bx = local & ((1 << sh) - 1), by = local >> sh;
  int n0 = bx * 32, k0 = by * 32;

  __shared__ float tile[32][33];
  int tx = threadIdx.x & 31, ty = threadIdx.x >> 5;   // 32 x 8
  #pragma unroll
  for (int i = 0; i < 4; i++)
    tile[ty + 8*i][tx] = W[(long)(k0 + ty + 8*i) * N + n0 + tx];
  __syncthreads();
  #pragma unroll
  for (int i = 0; i < 4; i++){
    int nn = ty + 8*i;
    Wt[(long)(n0 + nn) * K + k0 + tx] = f2b(tile[tx][nn]);
  }
}

typedef __bf16 bf16x8 __attribute__((ext_vector_type(8)));
typedef float f32x4 __attribute__((ext_vector_type(4)));

DEVFN void store_c(float* p, float v){ *p = v; }
DEVFN void store_c(u16* p, float v){ *p = f2b(v); }

DEVFN void gload16(const void* g, void* l){
  __builtin_amdgcn_global_load_lds((__attribute__((address_space(1))) void*)g,
                                   (__attribute__((address_space(3))) void*)l, 16, 0, 0);
}

// ======== 128x128 MFMA GEMM (NT), 4 waves, BK=64, swizzled LDS, counted vmcnt ========
// 64KB LDS double-buffer -> 2 blocks/CU. Best-measured of 4 variants tried
// (single-buf, tri-buf, 256^2, this): qkv 93us. Natural round-robin block order.
template <typename OutT>
__global__ __launch_bounds__(256) void gemm128_k(
    const u16* __restrict__ A, const u16* __restrict__ Bt, OutT* __restrict__ C,
    int M, int N, int K)
{
  __shared__ u16 As[2][128 * 64];
  __shared__ u16 Bs[2][128 * 64];
  int tid = threadIdx.x;
  int lane = tid & 63, wv = tid >> 6;
  int wm = wv & 1, wn = wv >> 1;          // 2 (M) x 2 (N); wave tile 64x64
  int l15 = lane & 15, lhi = lane >> 4;
  int m0 = blockIdx.y * 128, n0 = blockIdx.x * 128;
  const u16* Ab = A + (long)m0 * K;
  const u16* Bb = Bt + (long)n0 * K;

  auto stage = [&](int t, int bf){
    int k0 = t * 64;
    #pragma unroll
    for (int p = 0; p < 4; p++){
      int X = p * 256 + tid;              // 0..1023 (128 rows x 8 slots)
      int r = X >> 3, jj = X & 7;
      gload16(Ab + (long)r * K + k0 + ((jj ^ (r & 7)) * 8), &As[bf][(size_t)X * 8]);
    }
    #pragma unroll
    for (int p = 0; p < 4; p++){
      int X = p * 256 + tid;
      int r = X >> 3, jj = X & 7;
      gload16(Bb + (long)r * K + k0 + ((jj ^ (r & 7)) * 8), &Bs[bf][(size_t)X * 8]);
    }
  };

  f32x4 acc[4][4] = {};

  stage(0, 0);
  int T = K >> 6;
  for (int t = 0; t < T; t++){
    int bf = t & 1;
    if (t + 1 < T){
      stage(t + 1, bf ^ 1);
      asm volatile("s_waitcnt vmcnt(8)" ::: "memory");  // tile t's 8 loads landed
    } else {
      asm volatile("s_waitcnt vmcnt(0)" ::: "memory");
    }
    __builtin_amdgcn_s_barrier();

    #pragma unroll
    for (int kk = 0; kk < 64; kk += 32){
      int s = (kk >> 3) + lhi;
      bf16x8 av[4], bv[4];
      #pragma unroll
      for (int m = 0; m < 4; m++){
        int r = wm * 64 + m * 16 + l15;
        av[m] = *(const bf16x8*)&As[bf][r * 64 + ((s ^ (r & 7)) * 8)];
      }
      #pragma unroll
      for (int n = 0; n < 4; n++){
        int r = wn * 64 + n * 16 + l15;
        bv[n] = *(const bf16x8*)&Bs[bf][r * 64 + ((s ^ (r & 7)) * 8)];
      }
      #pragma unroll
      for (int m = 0; m < 4; m++)
        #pragma unroll
        for (int n = 0; n < 4; n++)
          acc[m][n] = __builtin_amdgcn_mfma_f32_16x16x32_bf16(av[m], bv[n], acc[m][n], 0, 0, 0);
    }
    asm volatile("" ::: "memory");
    __builtin_amdgcn_s_barrier();        // all reads of buf[bf] done before next stage overwrites
  }

  #pragma unroll
  for (int m = 0; m < 4; m++)
    #pragma unroll
    for (int n = 0; n < 4; n++)
      #pragma unroll
      for (int j = 0; j < 4; j++){
        long row = m0 + wm * 64 + m * 16 + lhi * 4 + j;
        long col = n0 + wn * 64 + n * 16 + l15;
        store_c(&C[row * (long)N + col], acc[m][n][j]);
      }
}

// ---------------- Wab pack ----------------
__global__ __launch_bounds__(256) void build_wab_k(
    const float* __restrict__ Wa, const float* __restrict__ Wb, u16* __restrict__ Wab)
{
  int idx = blockIdx.x * 256 + threadIdx.x;
  int c = idx >> 10, k = idx & 1023;
  float v = (c < 8) ? Wa[k * 8 + c] : Wb[k * 8 + (c - 8)];
  Wab[c * 1024 + k] = f2b(v);
}

// ---------------- alpha/beta via MFMA ----------------
__global__ __launch_bounds__(256) void ab_mfma_k(
    const u16* __restrict__ Xb, const u16* __restrict__ Wab,
    const float* __restrict__ A_log, const float* __restrict__ dt_bias,
    float* __restrict__ alpha, float* __restrict__ beta)
{
  __shared__ u16 Ws[16 * 1024];
  int tid = threadIdx.x, lane = tid & 63, wv = tid >> 6;
  #pragma unroll
  for (int p = 0; p < 8; p++){
    int X = p * 256 + tid;
    int r = X >> 7, s = X & 127;
    gload16(Wab + r * 1024 + (s ^ (r & 7)) * 8, &Ws[(size_t)X * 8]);
  }
  int l15 = lane & 15, lhi = lane >> 4;
  int row0 = blockIdx.x * 64 + wv * 16;
  const u16* Arow = Xb + (long)(row0 + l15) * 1024 + lhi * 8;
  __syncthreads();

  f32x4 acc = {0.f, 0.f, 0.f, 0.f};
  #pragma unroll 8
  for (int ks = 0; ks < 32; ks++){
    bf16x8 av = *(const bf16x8*)(Arow + ks * 32);
    int slot = ks * 4 + lhi;
    bf16x8 bv = *(const bf16x8*)&Ws[l15 * 1024 + (slot ^ (l15 & 7)) * 8];
    acc = __builtin_amdgcn_mfma_f32_16x16x32_bf16(av, bv, acc, 0, 0, 0);
  }

  int col = l15;
  float nA = 0.f, db = 0.f;
  if (col < 8){ nA = -expf(A_log[col]); db = dt_bias[col]; }
  #pragma unroll
  for (int j = 0; j < 4; j++){
    long row = row0 + lhi * 4 + j;
    float v = acc[j];
    if (col < 8){
      float xv = v + db;
      float sp = fmaxf(xv, 0.f) + log1pf(expf(-fabsf(xv)));
      alpha[row * 8 + col] = expf(nA * sp);
    } else {
      beta[row * 8 + (col - 8)] = sigm(v);
    }
  }
}

// ---------------- fused causal depthwise conv + SiLU (+ head L2 norm), 1 launch ----------------
// section: 0=q, 1=k, 2=v-lo, 3=v-hi; 64 threads = 128 channels; 8 timesteps/block.
__global__ __launch_bounds__(64) void conv_all_k(
    const u16* __restrict__ pre,
    const float* __restrict__ qcw, const float* __restrict__ qcb,
    const float* __restrict__ kcw, const float* __restrict__ kcb,
    const float* __restrict__ vcw, const float* __restrict__ vcb,
    u16* __restrict__ qn, u16* __restrict__ kn, u16* __restrict__ vn)
{
  int bid = blockIdx.x;
  int sec = bid & 3;
  int h = (bid >> 2) & 7;
  int tg = (bid >> 5) & 255;
  int b = bid >> 13;
  int t0 = tg * 8;
  int c2 = threadIdx.x * 2;
  const float *cw, *cb; int col; u16* outp; int ostride, ocol; bool norm;
  if (sec == 0){ int ch = h*128 + c2; cw = qcw + ch*4; cb = qcb + ch; col = ch;        outp = qn; ostride = 1024; ocol = ch; norm = true; }
  else if (sec == 1){ int ch = h*128 + c2; cw = kcw + ch*4; cb = kcb + ch; col = 1024+ch; outp = kn; ostride = 1024; ocol = ch; norm = true; }
  else { int z = sec - 2; int ch = h*256 + z*128 + c2; cw = vcw + ch*4; cb = vcb + ch; col = 2048+ch; outp = vn; ostride = 2048; ocol = ch; norm = false; }

  const u16* base = pre + ((long)b * CT) * 4096 + col;
  float wa = cw[0], wb = cw[1], wc = cw[2], wd = cw[3];
  float wa1 = cw[4], wb1 = cw[5], wc1 = cw[6], wd1 = cw[7];
  float bs0 = cb[0], bs1 = cb[1];

  u32 rr[11];
  #pragma unroll
  for (int i = 0; i < 11; i++){
    int t = t0 - 3 + i;
    rr[i] = (t >= 0) ? *(const u32*)(base + (long)t * 4096) : 0u;
  }
  #pragma unroll
  for (int tt = 0; tt < 8; tt++){
    int t = t0 + tt;
    float x0a = b2f((u16)(rr[tt] & 0xffffu)),     x1a = b2f((u16)(rr[tt] >> 16));
    float x0b = b2f((u16)(rr[tt + 1] & 0xffffu)), x1b = b2f((u16)(rr[tt + 1] >> 16));
    float x0c = b2f((u16)(rr[tt + 2] & 0xffffu)), x1c = b2f((u16)(rr[tt + 2] >> 16));
    float x0d = b2f((u16)(rr[tt + 3] & 0xffffu)), x1d = b2f((u16)(rr[tt + 3] >> 16));
    float a0 = fmaf(wa, x0a, fmaf(wb, x0b, fmaf(wc, x0c, fmaf(wd, x0d, bs0))));
    float a1 = fmaf(wa1, x1a, fmaf(wb1, x1b, fmaf(wc1, x1c, fmaf(wd1, x1d, bs1))));
    float y0 = a0 * sigm(a0), y1 = a1 * sigm(a1);
    if (norm){
      float ss = y0 * y0 + y1 * y1;
      #pragma unroll
      for (int off = 1; off < 64; off <<= 1) ss += __shfl_xor(ss, off);
      float inv = 1.f / fmaxf(sqrtf(ss), 1e-12f);
      y0 *= inv; y1 *= inv;
    }
    u32 r = (u32)f2b(y0) | ((u32)f2b(y1) << 16);
    *(u32*)(outp + ((long)b * CT + t) * ostride + ocol) = r;
  }
}

// ============ chunked delta rule: per-chunk metadata (L=32) ============
__global__ __launch_bounds__(256) void chunk_meta_k(
    const u16* __restrict__ qn, const u16* __restrict__ kn, const u16* __restrict__ vn,
    const float* __restrict__ alpha, const float* __restrict__ beta,
    u16* __restrict__ TGK_g, u16* __restrict__ TVT_g, u16* __restrict__ P_g,
    u16* __restrict__ KTS_g, float* __restrict__ scal_g)
{
  int bid = blockIdx.x;
  int c = bid & 63, bh = bid >> 6;
  int b = bh >> 3, h = bh & 7;
  long rowb = (long)b * CT + c * 32;
  int tid = threadIdx.x, lane = tid & 63, wv = tid >> 6;
  int l15 = lane & 15, lhi = lane >> 4;
  int mt = wv & 1, nt = wv >> 1;

  __shared__ u16 Kc[4096], Qc[4096], Vl[8192];
  __shared__ u16 Vt[10240];    // [v 256][s 32] stride 40
  __shared__ u16 KTG[5120];    // [k 128][s 32] stride 40
  __shared__ u16 TinvL[1280];  // [s 32][s' 32] stride 40
  __shared__ float Al[32 * 33];
  __shared__ float al_s[32], be_s[32], cums[33], bscal[32], gsl[32];

  #pragma unroll
  for (int p = 0; p < 2; p++){
    int X = p * 256 + tid; int r = X >> 4, jj = X & 15;
    gload16(kn + ((rowb + r) * 8 + h) * 128 + (jj ^ (r & 7)) * 8, &Kc[(size_t)X * 8]);
  }
  #pragma unroll
  for (int p = 0; p < 2; p++){
    int X = p * 256 + tid; int r = X >> 4, jj = X & 15;
    gload16(qn + ((rowb + r) * 8 + h) * 128 + (jj ^ (r & 7)) * 8, &Qc[(size_t)X * 8]);
  }
  #pragma unroll
  for (int p = 0; p < 4; p++){
    int X = p * 256 + tid; int r = X >> 5, cc = X & 31;
    gload16(vn + ((rowb + r) * 8 + h) * 256 + cc * 8, &Vl[(size_t)X * 8]);
  }
  if (tid < 32) al_s[tid] = alpha[(rowb + tid) * 8 + h];
  else if (tid < 64) be_s[tid - 32] = beta[(rowb + tid - 32) * 8 + h];
  __syncthreads();
  if (tid == 0){
    float cacc = 0.f; cums[0] = 0.f;
    for (int j = 0; j < 32; j++){ cacc += logf(al_s[j]); cums[j + 1] = cacc; }
  }
  __syncthreads();
  if (tid < 32){
    bscal[tid] = be_s[tid] * expf(cums[32] - cums[tid + 1]);
    gsl[tid] = expf(cums[tid]);
  }
  asm volatile("s_waitcnt vmcnt(0)" ::: "memory");
  __syncthreads();

  #pragma unroll
  for (int i = 0; i < 16; i++){
    u32 lo = Vl[(2 * i) * 256 + tid];
    u32 hi = Vl[(2 * i + 1) * 256 + tid];
    *(u32*)&Vt[tid * 40 + 2 * i] = lo | (hi << 16);
  }

  f32x4 rk = {0.f,0.f,0.f,0.f}, rq = {0.f,0.f,0.f,0.f};
  int ra = mt * 16 + l15, rb = nt * 16 + l15;
  #pragma unroll
  for (int ks = 0; ks < 4; ks++){
    int slot = ks * 4 + lhi;
    bf16x8 ak = *(const bf16x8*)&Kc[ra * 128 + (slot ^ (ra & 7)) * 8];
    bf16x8 aq = *(const bf16x8*)&Qc[ra * 128 + (slot ^ (ra & 7)) * 8];
    bf16x8 bk = *(const bf16x8*)&Kc[rb * 128 + (slot ^ (rb & 7)) * 8];
    rk = __builtin_amdgcn_mfma_f32_16x16x32_bf16(ak, bk, rk, 0, 0, 0);
    rq = __builtin_amdgcn_mfma_f32_16x16x32_bf16(aq, bk, rq, 0, 0, 0);
  }
  int s_ = nt * 16 + l15;
  long pb_ = (long)bid * 1024;
  #pragma unroll
  for (int j = 0; j < 4; j++){
    int i_ = mt * 16 + lhi * 4 + j;
    float e = (s_ < i_) ? expf(cums[i_] - cums[s_ + 1]) * be_s[s_] : 0.f;
    Al[i_ * 33 + s_] = rk[j] * e;
    P_g[pb_ + i_ * 32 + s_] = f2b(rq[j] * e);
  }
  __syncthreads();

  if (tid < 32){
    float x[32];
    #pragma unroll
    for (int i = 0; i < 32; i++) x[i] = (i == tid) ? 1.f : 0.f;
    #pragma unroll
    for (int s = 0; s < 31; s++){
      float xs = x[s];
      #pragma unroll
      for (int i = s + 1; i < 32; i++) x[i] = fmaf(-Al[i * 33 + s], xs, x[i]);
    }
    #pragma unroll
    for (int i = 0; i < 32; i++) TinvL[i * 40 + tid] = f2b(x[i]);
    scal_g[(long)bid * 48 + tid] = gsl[tid];
    if (tid == 0) scal_g[(long)bid * 48 + 32] = expf(cums[32]);
  } else if (tid >= 64){
    int t0 = tid - 64;
    #pragma unroll
    for (int e2 = 0; e2 < 22; e2++){
      int e = t0 + e2 * 192;
      if (e < 4096){
        int k = e >> 5, s2 = e & 31;
        int slot = k >> 3;
        float kv = b2f(Kc[s2 * 128 + (slot ^ (s2 & 7)) * 8 + (k & 7)]);
        KTS_g[(long)bid * 4096 + k * 32 + s2] = f2b(kv * bscal[s2]);
        KTG[k * 40 + s2] = f2b(kv * gsl[s2]);
      }
    }
  }
  __syncthreads();

  long tb = (long)bid * 4096;
  #pragma unroll
  for (int p = 0; p < 4; p++){
    int idx = wv * 4 + p; int ts = idx >> 3, tk = idx & 7;
    bf16x8 aT = *(const bf16x8*)&TinvL[(ts * 16 + l15) * 40 + lhi * 8];
    bf16x8 bK2 = *(const bf16x8*)&KTG[(tk * 16 + l15) * 40 + lhi * 8];
    f32x4 z = {0.f,0.f,0.f,0.f};
    f32x4 d = __builtin_amdgcn_mfma_f32_16x16x32_bf16(aT, bK2, z, 0, 0, 0);
    #pragma unroll
    for (int j = 0; j < 4; j++)
      TGK_g[tb + (ts * 16 + lhi * 4 + j) * 128 + tk * 16 + l15] = f2b(d[j]);
  }
  long vb = (long)bid * 8192;
  #pragma unroll
  for (int p = 0; p < 8; p++){
    int idx = wv * 8 + p; int tv = idx >> 1, ts2 = idx & 1;
    bf16x8 aV = *(const bf16x8*)&Vt[(tv * 16 + l15) * 40 + lhi * 8];
    bf16x8 bT2 = *(const bf16x8*)&TinvL[(ts2 * 16 + l15) * 40 + lhi * 8];
    f32x4 z = {0.f,0.f,0.f,0.f};
    f32x4 d = __builtin_amdgcn_mfma_f32_16x16x32_bf16(aV, bT2, z, 0, 0, 0);
    #pragma unroll
    for (int j = 0; j < 4; j++)
      TVT_g[vb + (tv * 16 + lhi * 4 + j) * 32 + ts2 * 16 + l15] = f2b(d[j]);
  }
}

// ============ chunked delta rule: main scan — EXACT R10 structure (proven) ============
__global__ __launch_bounds__(256) void chunk_scan_k(
    const u16* __restrict__ qn, const u16* __restrict__ TGK_g, const u16* __restrict__ TVT_g,
    const u16* __restrict__ P_g, const u16* __restrict__ KTS_g,
    const float* __restrict__ scal_g, const float* __restrict__ prev,
    u16* __restrict__ obuf, float* __restrict__ fstate)
{
  int bid = blockIdx.x;
  int bh = bid & 31, vs = bid >> 5;
  int b = bh >> 3, h = bh & 7;
  int tid = threadIdx.x, lane = tid & 63, wv = tid >> 6;
  int l15 = lane & 15, lhi = lane >> 4;
  int mv = wv & 1, nn = wv >> 1;

  __shared__ u16 TG[2][4096];
  __shared__ u16 Qc[2][4096];
  __shared__ u16 TVs[2][1024];
  __shared__ float scal[2][48];
  __shared__ u16 KT[2][4096];
  __shared__ u16 Ps[2][1024];
  __shared__ u16 Sb[32 * 136];
  __shared__ u16 Ub[32 * 40];

  auto issue_g1 = [&](int c, int bf){   // 8 loads/wave
    long cb_ = (long)bh * 64 + c;
    const u16* Tb_ = TGK_g + cb_ * 4096;
    #pragma unroll
    for (int p = 0; p < 2; p++){
      int X = p * 256 + tid; int r = X >> 4, jj = X & 15;
      gload16(Tb_ + r * 128 + (jj ^ (r & 7)) * 8, &TG[bf][(size_t)X * 8]);
    }
    long rowb = (long)b * CT + c * 32;
    #pragma unroll
    for (int p = 0; p < 2; p++){
      int X = p * 256 + tid; int r = X >> 4, jj = X & 15;
      gload16(qn + ((rowb + r) * 8 + h) * 128 + (jj ^ (r & 7)) * 8, &Qc[bf][(size_t)X * 8]);
    }
    if (lane < 32){
      int X = wv * 32 + lane; int r = X >> 2, jj = X & 3;
      gload16(TVT_g + cb_ * 8192 + (vs * 32 + r) * 32 + (jj ^ swz3(r)) * 8, &TVs[bf][(size_t)X * 8]);
    }
    long sbase = cb_ * 48;
    #pragma unroll
    for (int p = 0; p < 3; p++){
      int X = wv * 3 + p;
      if (lane == 0) gload16(scal_g + sbase + X * 4, &scal[bf][X * 4]);
    }
  };
  auto issue_g2 = [&](int c, int bf){   // 3 loads/wave
    long cb_ = (long)bh * 64 + c;
    const u16* Kb_ = KTS_g + cb_ * 4096;
    #pragma unroll
    for (int p = 0; p < 2; p++){
      int X = p * 256 + tid; int r = X >> 2, jj = X & 3;
      gload16(Kb_ + (r * 4 + (jj ^ swz3(r))) * 8, &KT[bf][(size_t)X * 8]);
    }
    if (lane < 32){
      int X = wv * 32 + lane; int r = X >> 2, jj = X & 3;
      gload16(P_g + cb_ * 1024 + (r * 4 + (jj ^ swz3(r))) * 8, &Ps[bf][(size_t)X * 8]);
    }
  };

  // ---- prologue: g1(0) then g2(0); prev state -> regs + Sb
  issue_g1(0, 0);
  issue_g2(0, 0);
  f32x4 st[4];
  {
    const float* pbv = prev + ((long)bh * 128) * 256 + vs * 32;
    #pragma unroll
    for (int tt = 0; tt < 4; tt++){
      int k = (nn * 4 + tt) * 16 + l15;
      #pragma unroll
      for (int j = 0; j < 4; j++){
        int v = mv * 16 + lhi * 4 + j;
        st[tt][j] = pbv[(long)k * 256 + v];
      }
    }
  }
  #pragma unroll
  for (int tt = 0; tt < 4; tt++){
    int k = (nn * 4 + tt) * 16 + l15;
    #pragma unroll
    for (int j = 0; j < 4; j++){
      int v = mv * 16 + lhi * 4 + j;
      Sb[v * 136 + k] = f2b(st[tt][j]);
    }
  }
  asm volatile("s_waitcnt vmcnt(3) lgkmcnt(0)" ::: "memory");
  __builtin_amdgcn_s_barrier();

  int rv = mv * 16 + l15, ri = nn * 16 + l15;
  for (int c = 0; c < 64; ++c){
    int bf = c & 1;
    // ---- Phase A: Us = TGK@S, o1 = Q@S; U = TVT - Us -> Ub
    f32x4 us = {0.f,0.f,0.f,0.f}, o1 = {0.f,0.f,0.f,0.f};
    #pragma unroll
    for (int ks = 0; ks < 4; ks++){
      bf16x8 aS = *(const bf16x8*)&Sb[rv * 136 + ks * 32 + lhi * 8];
      int slot = ks * 4 + lhi;
      bf16x8 bT = *(const bf16x8*)&TG[bf][ri * 128 + (slot ^ (ri & 7)) * 8];
      bf16x8 bQ = *(const bf16x8*)&Qc[bf][ri * 128 + (slot ^ (ri & 7)) * 8];
      us = __builtin_amdgcn_mfma_f32_16x16x32_bf16(aS, bT, us, 0, 0, 0);
      o1 = __builtin_amdgcn_mfma_f32_16x16x32_bf16(aS, bQ, o1, 0, 0, 0);
    }
    if (c + 1 < 64) issue_g1(c + 1, bf ^ 1);
    #pragma unroll
    for (int j = 0; j < 4; j++){
      int v = mv * 16 + lhi * 4 + j;
      float tv = b2f(TVs[bf][v * 32 + ((ri >> 3) ^ swz3(v)) * 8 + (ri & 7)]);
      Ub[v * 40 + ri] = f2b(tv - us[j]);
    }
    asm volatile("s_waitcnt lgkmcnt(0)" ::: "memory");
    if (c + 1 < 64) asm volatile("s_waitcnt vmcnt(8)" ::: "memory");
    else            asm volatile("s_waitcnt vmcnt(0)" ::: "memory");
    __builtin_amdgcn_s_barrier();

    // ---- Phase B: O = U@P^T + gi*o1 ; S' = Gt*S + U@KTS^T
    float Gt = scal[bf][32];
    f32x4 oacc;
    {
      bf16x8 aU = *(const bf16x8*)&Ub[rv * 40 + lhi * 8];
      bf16x8 bP = *(const bf16x8*)&Ps[bf][ri * 32 + (lhi ^ swz3(ri)) * 8];
      f32x4 z = {0.f,0.f,0.f,0.f};
      oacc = __builtin_amdgcn_mfma_f32_16x16x32_bf16(aU, bP, z, 0, 0, 0);
      #pragma unroll
      for (int tt = 0; tt < 4; tt++){
        int rk_ = (nn * 4 + tt) * 16 + l15;
        bf16x8 bK = *(const bf16x8*)&KT[bf][rk_ * 32 + (lhi ^ swz3(rk_)) * 8];
        f32x4 ci = st[tt] * Gt;
        st[tt] = __builtin_amdgcn_mfma_f32_16x16x32_bf16(aU, bK, ci, 0, 0, 0);
      }
    }
    {
      float gi = scal[bf][ri];
      ushort4 pk;
      pk.x = f2b(oacc[0] + gi * o1[0]);
      pk.y = f2b(oacc[1] + gi * o1[1]);
      pk.z = f2b(oacc[2] + gi * o1[2]);
      pk.w = f2b(oacc[3] + gi * o1[3]);
      *(ushort4*)&obuf[(((long)bh * CT) + c * 32 + ri) * 256 + vs * 32 + mv * 16 + lhi * 4] = pk;
    }
    if (c + 1 < 64) issue_g2(c + 1, bf ^ 1);
    #pragma unroll
    for (int tt = 0; tt < 4; tt++){
      int k = (nn * 4 + tt) * 16 + l15;
      #pragma unroll
      for (int j = 0; j < 4; j++){
        int v = mv * 16 + lhi * 4 + j;
        Sb[v * 136 + k] = f2b(st[tt][j]);
      }
    }
    asm volatile("s_waitcnt lgkmcnt(0)" ::: "memory");
    if (c + 1 < 64) asm volatile("s_waitcnt vmcnt(3)" ::: "memory");
    else            asm volatile("s_waitcnt vmcnt(0)" ::: "memory");
    __builtin_amdgcn_s_barrier();
  }

  // ---- epilogue: final state
  {
    float* fb = fstate + ((long)bh * 128) * 256 + vs * 32;
    #pragma unroll
    for (int tt = 0; tt < 4; tt++){
      int k = (nn * 4 + tt) * 16 + l15;
      #pragma unroll
      for (int j = 0; j < 4; j++){
        int v = mv * 16 + lhi * 4 + j;
        fb[(long)k * 256 + v] = st[tt][j];
      }
    }
  }
}

// ---------------- gated RMSNorm: one wave per (b,t,h) ----------------
__global__ __launch_bounds__(256) void rms_gate_k(
    const u16* __restrict__ o, const u16* __restrict__ gate,
    const float* __restrict__ nw, u16* __restrict__ ofin)
{
  long idx = (long)blockIdx.x * 4 + (threadIdx.x >> 6);
  int lane = threadIdx.x & 63;
  int h = (int)(idx & 7);
  long bt = idx >> 3;
  int b = (int)(bt >> 11);
  long t = bt & (CT - 1);
  long obase = (((long)(b * 8 + h)) * CT + t) * CDV + lane * 4;
  long base = idx * CDV + lane * 4;
  ushort4 o4 = *(const ushort4*)(o + obase);
  float ox = b2f(o4.x), oy = b2f(o4.y), oz = b2f(o4.z), ow = b2f(o4.w);
  float ss = ox*ox + oy*oy + oz*oz + ow*ow;
  #pragma unroll
  for (int off = 1; off < 64; off <<= 1) ss += __shfl_xor(ss, off);
  float r = rsqrtf(ss * (1.f / CDV) + 1e-5f);
  ushort4 g4 = *(const ushort4*)(gate + base);
  float w0 = nw[lane*4], w1 = nw[lane*4+1], w2 = nw[lane*4+2], w3 = nw[lane*4+3];
  ushort4 res;
  res.x = f2b(ox * r * w0 * sigm(b2f(g4.x)));
  res.y = f2b(oy * r * w1 * sigm(b2f(g4.y)));
  res.z = f2b(oz * r * w2 * sigm(b2f(g4.z)));
  res.w = f2b(ow * r * w3 * sigm(b2f(g4.w)));
  *(ushort4*)(ofin + base) = res;
}

// ---------------- host launch ----------------
extern "C" void kernel_launch(void* const* d_in, const int* in_sizes, int n_in,
                              void* d_out, int out_size, void* d_ws, size_t ws_size,
                              hipStream_t stream)
{
  (void)in_sizes; (void)n_in; (void)out_size; (void)ws_size;
  const float* X    = (const float*)d_in[0];
  const float* prev = (const float*)d_in[1];
  const float* Wq   = (const float*)d_in[2];
  const float* Wk   = (const float*)d_in[3];
  const float* Wv   = (const float*)d_in[4];
  const float* Wa   = (const float*)d_in[5];
  const float* Wb   = (const float*)d_in[6];
  const float* Wg   = (const float*)d_in[7];
  const float* Wo   = (const float*)d_in[8];
  const float* qcw  = (const float*)d_in[9];
  const float* qcb  = (const float*)d_in[10];
  const float* kcw  = (const float*)d_in[11];
  const float* kcb  = (const float*)d_in[12];
  const float* vcw  = (const float*)d_in[13];
  const float* vcb  = (const float*)d_in[14];
  const float* onw  = (const float*)d_in[15];
  const float* Alog = (const float*)d_in[16];
  const float* dtb  = (const float*)d_in[17];

  float* out = (float*)d_out;
  float* fstate = out + (long)CB * CT * CD;

  char* ws = (char*)d_ws;
  size_t off = 0;
  auto alloc = [&](size_t bytes) -> char* {
    char* p = ws + off;
    off += (bytes + 255) & ~(size_t)255;
    return p;
  };
  u16* Xb     = (u16*)alloc(NROW * CD * 2);
  u16* Wqkvt  = (u16*)alloc((size_t)4096 * 1024 * 2);
  u16* Wgt    = (u16*)alloc((size_t)2048 * 1024 * 2);
  u16* Wot    = (u16*)alloc((size_t)1024 * 2048 * 2);
  u16* qkvpre = (u16*)alloc(NROW * 4096 * 2);
  u16* gpre   = (u16*)alloc(NROW * 2048 * 2);
  float* alpha = (float*)alloc(NROW * 8 * 4);
  float* beta  = (float*)alloc(NROW * 8 * 4);
  u16* qn   = (u16*)alloc(NROW * 1024 * 2);
  u16* kn   = (u16*)alloc(NROW * 1024 * 2);
  u16* vn   = (u16*)alloc(NROW * 2048 * 2);
  u16* ofin = (u16*)alloc(NROW * 2048 * 2);
  u16* Wab  = (u16*)alloc((size_t)16 * 1024 * 2);
  // aliases (lifetime-checked):
  // TGK -> Xb (EXACT); TVT -> ofin (EXACT); qkvpre partition:
  //   obuf [0..16,777,216) | P [16,777,216..18,874,368) | scal [18,874,368..19,070,976)
  //   KTS [19,136,512..27,525,120).  Wot never aliased.
  u16* TGK_g  = Xb;
  u16* TVT_g  = ofin;
  u16* obuf   = qkvpre;
  u16* P_g    = qkvpre + (size_t)16777216;
  float* scal_g = (float*)(qkvpre + (size_t)18874368);
  u16* KTS_g  = qkvpre + (size_t)19136512;

  cast_f32_bf16_k<<<2048, 256, 0, stream>>>(X, Xb, NROW * CD / 4);
  build_wab_k<<<64, 256, 0, stream>>>(Wa, Wb, Wab);
  transpose_all_k<<<8192, 256, 0, stream>>>(Wq, Wk, Wv, Wg, Wo, Wqkvt, Wgt, Wot);

  gemm128_k<u16><<<dim3(32, 64), 256, 0, stream>>>(Xb, Wqkvt, qkvpre, 8192, 4096, 1024);
  gemm128_k<u16><<<dim3(16, 64), 256, 0, stream>>>(Xb, Wgt, gpre, 8192, 2048, 1024);
  ab_mfma_k<<<128, 256, 0, stream>>>(Xb, Wab, Alog, dtb, alpha, beta);

  conv_all_k<<<CB * (CT / 8) * CH * 4, 64, 0, stream>>>(qkvpre, qcw, qcb, kcw, kcb, vcw, vcb,
                                                        qn, kn, vn);

  chunk_meta_k<<<2048, 256, 0, stream>>>(qn, kn, vn, alpha, beta,
                                         TGK_g, TVT_g, P_g, KTS_g, scal_g);
  chunk_scan_k<<<256, 256, 0, stream>>>(qn, TGK_g, TVT_g, P_g, KTS_g, scal_g,
                                        prev, obuf, fstate);

  rms_gate_k<<<CB * CT * CH / 4, 256, 0, stream>>>(obuf, gpre, onw, ofin);
  gemm128_k<float><<<dim3(8, 64), 256, 0, stream>>>(ofin, Wot, out, 8192, 1024, 2048);
}

// Round 18
// 381.423 us; speedup vs baseline: 1.0711x; 1.0116x over previous
//
#include <hip/hip_runtime.h>
#include <stdint.h>

typedef unsigned short u16;
typedef unsigned int u32;

#define DEVFN __device__ __forceinline__

constexpr int CB = 4;
constexpr int CT = 2048;
constexpr int CD = 1024;
constexpr int CH = 8;
constexpr int CDK = 128;
constexpr int CDV = 256;
constexpr long NROW = (long)CB * CT;   // 8192

DEVFN float b2f(u16 s){ return __uint_as_float(((u32)s) << 16); }
DEVFN u16 f2b(float f){
  u32 u = __float_as_uint(f);
  u32 r = (u + 0x7fffu + ((u >> 16) & 1u)) >> 16;
  return (u16)r;
}
DEVFN float sigm(float x){ return 1.f / (1.f + expf(-x)); }
DEVFN int swz3(int r){ return (r ^ (r >> 2)) & 3; }

// ---------------- fused prep: cast X->bf16 | pack Wab | transpose 5 weights ----------------
// sections: [0,2048) cast; [2048,2112) wab; [2112,10304) transpose.
__global__ __launch_bounds__(256) void prep_all_k(
    const float* __restrict__ X, u16* __restrict__ Xb,
    const float* __restrict__ Wa, const float* __restrict__ Wb, u16* __restrict__ Wab,
    const float* __restrict__ Wq, const float* __restrict__ Wk, const float* __restrict__ Wv,
    const float* __restrict__ Wg, const float* __restrict__ Wo,
    u16* __restrict__ Wqkvt, u16* __restrict__ Wgt, u16* __restrict__ Wot)
{
  __shared__ float tile[32][33];
  int bid = blockIdx.x;
  if (bid < 2048){
    long i = (long)bid * 256 + threadIdx.x;
    long n4 = NROW * CD / 4;
    long stride = 2048L * 256;
    for (; i < n4; i += stride){
      float4 v = ((const float4*)X)[i];
      ushort4 r;
      r.x = f2b(v.x); r.y = f2b(v.y); r.z = f2b(v.z); r.w = f2b(v.w);
      ((ushort4*)Xb)[i] = r;
    }
    return;
  }
  if (bid < 2112){
    int idx = (bid - 2048) * 256 + threadIdx.x;   // 16384
    int c = idx >> 10, k = idx & 1023;
    float v = (c < 8) ? Wa[k * 8 + c] : Wb[k * 8 + (c - 8)];
    Wab[c * 1024 + k] = f2b(v);
    return;
  }
  int tb = bid - 2112;
  const float* W; u16* Wt; int K, N, local;
  if (tb < 1024){ W = Wq; Wt = Wqkvt; K = 1024; N = 1024; local = tb; }
  else if (tb < 2048){ W = Wk; Wt = Wqkvt + (size_t)1024 * 1024; K = 1024; N = 1024; local = tb - 1024; }
  else if (tb < 4096){ W = Wv; Wt = Wqkvt + (size_t)2048 * 1024; K = 1024; N = 2048; local = tb - 2048; }
  else if (tb < 6144){ W = Wg; Wt = Wgt; K = 1024; N = 2048; local = tb - 4096; }
  else { W = Wo; Wt = Wot; K = 2048; N = 1024; local = tb - 6144; }
  int sh = (N == 1024) ? 5 : 6;
  int bx = local & ((1 << sh) - 1), by = local >> sh;
  int n0 = bx * 32, k0 = by * 32;

  int tx = threadIdx.x & 31, ty = threadIdx.x >> 5;   // 32 x 8
  #pragma unroll
  for (int i = 0; i < 4; i++)
    tile[ty + 8*i][tx] = W[(long)(k0 + ty + 8*i) * N + n0 + tx];
  __syncthreads();
  #pragma unroll
  for (int i = 0; i < 4; i++){
    int nn = ty + 8*i;
    Wt[(long)(n0 + nn) * K + k0 + tx] = f2b(tile[tx][nn]);
  }
}

typedef __bf16 bf16x8 __attribute__((ext_vector_type(8)));
typedef float f32x4 __attribute__((ext_vector_type(4)));

DEVFN void store_c(float* p, float v){ *p = v; }
DEVFN void store_c(u16* p, float v){ *p = f2b(v); }

DEVFN void gload16(const void* g, void* l){
  __builtin_amdgcn_global_load_lds((__attribute__((address_space(1))) void*)g,
                                   (__attribute__((address_space(3))) void*)l, 16, 0, 0);
}

// ======== 128x128 MFMA GEMM (NT), 4 waves, BK=64, swizzled LDS, counted vmcnt ========
// 64KB LDS double-buffer -> 2 blocks/CU. Best-measured of 4 variants tried.
template <typename OutT>
__global__ __launch_bounds__(256) void gemm128_k(
    const u16* __restrict__ A, const u16* __restrict__ Bt, OutT* __restrict__ C,
    int M, int N, int K)
{
  __shared__ u16 As[2][128 * 64];
  __shared__ u16 Bs[2][128 * 64];
  int tid = threadIdx.x;
  int lane = tid & 63, wv = tid >> 6;
  int wm = wv & 1, wn = wv >> 1;          // 2 (M) x 2 (N); wave tile 64x64
  int l15 = lane & 15, lhi = lane >> 4;
  int m0 = blockIdx.y * 128, n0 = blockIdx.x * 128;
  const u16* Ab = A + (long)m0 * K;
  const u16* Bb = Bt + (long)n0 * K;

  auto stage = [&](int t, int bf){
    int k0 = t * 64;
    #pragma unroll
    for (int p = 0; p < 4; p++){
      int X = p * 256 + tid;              // 0..1023 (128 rows x 8 slots)
      int r = X >> 3, jj = X & 7;
      gload16(Ab + (long)r * K + k0 + ((jj ^ (r & 7)) * 8), &As[bf][(size_t)X * 8]);
    }
    #pragma unroll
    for (int p = 0; p < 4; p++){
      int X = p * 256 + tid;
      int r = X >> 3, jj = X & 7;
      gload16(Bb + (long)r * K + k0 + ((jj ^ (r & 7)) * 8), &Bs[bf][(size_t)X * 8]);
    }
  };

  f32x4 acc[4][4] = {};

  stage(0, 0);
  int T = K >> 6;
  for (int t = 0; t < T; t++){
    int bf = t & 1;
    if (t + 1 < T){
      stage(t + 1, bf ^ 1);
      asm volatile("s_waitcnt vmcnt(8)" ::: "memory");  // tile t's 8 loads landed
    } else {
      asm volatile("s_waitcnt vmcnt(0)" ::: "memory");
    }
    __builtin_amdgcn_s_barrier();

    #pragma unroll
    for (int kk = 0; kk < 64; kk += 32){
      int s = (kk >> 3) + lhi;
      bf16x8 av[4], bv[4];
      #pragma unroll
      for (int m = 0; m < 4; m++){
        int r = wm * 64 + m * 16 + l15;
        av[m] = *(const bf16x8*)&As[bf][r * 64 + ((s ^ (r & 7)) * 8)];
      }
      #pragma unroll
      for (int n = 0; n < 4; n++){
        int r = wn * 64 + n * 16 + l15;
        bv[n] = *(const bf16x8*)&Bs[bf][r * 64 + ((s ^ (r & 7)) * 8)];
      }
      #pragma unroll
      for (int m = 0; m < 4; m++)
        #pragma unroll
        for (int n = 0; n < 4; n++)
          acc[m][n] = __builtin_amdgcn_mfma_f32_16x16x32_bf16(av[m], bv[n], acc[m][n], 0, 0, 0);
    }
    asm volatile("" ::: "memory");
    __builtin_amdgcn_s_barrier();        // all reads of buf[bf] done before next stage overwrites
  }

  #pragma unroll
  for (int m = 0; m < 4; m++)
    #pragma unroll
    for (int n = 0; n < 4; n++)
      #pragma unroll
      for (int j = 0; j < 4; j++){
        long row = m0 + wm * 64 + m * 16 + lhi * 4 + j;
        long col = n0 + wn * 64 + n * 16 + l15;
        store_c(&C[row * (long)N + col], acc[m][n][j]);
      }
}

// ---------------- alpha/beta via MFMA ----------------
__global__ __launch_bounds__(256) void ab_mfma_k(
    const u16* __restrict__ Xb, const u16* __restrict__ Wab,
    const float* __restrict__ A_log, const float* __restrict__ dt_bias,
    float* __restrict__ alpha, float* __restrict__ beta)
{
  __shared__ u16 Ws[16 * 1024];
  int tid = threadIdx.x, lane = tid & 63, wv = tid >> 6;
  #pragma unroll
  for (int p = 0; p < 8; p++){
    int X = p * 256 + tid;
    int r = X >> 7, s = X & 127;
    gload16(Wab + r * 1024 + (s ^ (r & 7)) * 8, &Ws[(size_t)X * 8]);
  }
  int l15 = lane & 15, lhi = lane >> 4;
  int row0 = blockIdx.x * 64 + wv * 16;
  const u16* Arow = Xb + (long)(row0 + l15) * 1024 + lhi * 8;
  __syncthreads();

  f32x4 acc = {0.f, 0.f, 0.f, 0.f};
  #pragma unroll 8
  for (int ks = 0; ks < 32; ks++){
    bf16x8 av = *(const bf16x8*)(Arow + ks * 32);
    int slot = ks * 4 + lhi;
    bf16x8 bv = *(const bf16x8*)&Ws[l15 * 1024 + (slot ^ (l15 & 7)) * 8];
    acc = __builtin_amdgcn_mfma_f32_16x16x32_bf16(av, bv, acc, 0, 0, 0);
  }

  int col = l15;
  float nA = 0.f, db = 0.f;
  if (col < 8){ nA = -expf(A_log[col]); db = dt_bias[col]; }
  #pragma unroll
  for (int j = 0; j < 4; j++){
    long row = row0 + lhi * 4 + j;
    float v = acc[j];
    if (col < 8){
      float xv = v + db;
      float sp = fmaxf(xv, 0.f) + log1pf(expf(-fabsf(xv)));
      alpha[row * 8 + col] = expf(nA * sp);
    } else {
      beta[row * 8 + (col - 8)] = sigm(v);
    }
  }
}

// ---------------- fused causal depthwise conv + SiLU (+ head L2 norm), 1 launch ----------------
__global__ __launch_bounds__(64) void conv_all_k(
    const u16* __restrict__ pre,
    const float* __restrict__ qcw, const float* __restrict__ qcb,
    const float* __restrict__ kcw, const float* __restrict__ kcb,
    const float* __restrict__ vcw, const float* __restrict__ vcb,
    u16* __restrict__ qn, u16* __restrict__ kn, u16* __restrict__ vn)
{
  int bid = blockIdx.x;
  int sec = bid & 3;
  int h = (bid >> 2) & 7;
  int tg = (bid >> 5) & 255;
  int b = bid >> 13;
  int t0 = tg * 8;
  int c2 = threadIdx.x * 2;
  const float *cw, *cb; int col; u16* outp; int ostride, ocol; bool norm;
  if (sec == 0){ int ch = h*128 + c2; cw = qcw + ch*4; cb = qcb + ch; col = ch;        outp = qn; ostride = 1024; ocol = ch; norm = true; }
  else if (sec == 1){ int ch = h*128 + c2; cw = kcw + ch*4; cb = kcb + ch; col = 1024+ch; outp = kn; ostride = 1024; ocol = ch; norm = true; }
  else { int z = sec - 2; int ch = h*256 + z*128 + c2; cw = vcw + ch*4; cb = vcb + ch; col = 2048+ch; outp = vn; ostride = 2048; ocol = ch; norm = false; }

  const u16* base = pre + ((long)b * CT) * 4096 + col;
  float wa = cw[0], wb = cw[1], wc = cw[2], wd = cw[3];
  float wa1 = cw[4], wb1 = cw[5], wc1 = cw[6], wd1 = cw[7];
  float bs0 = cb[0], bs1 = cb[1];

  u32 rr[11];
  #pragma unroll
  for (int i = 0; i < 11; i++){
    int t = t0 - 3 + i;
    rr[i] = (t >= 0) ? *(const u32*)(base + (long)t * 4096) : 0u;
  }
  #pragma unroll
  for (int tt = 0; tt < 8; tt++){
    int t = t0 + tt;
    float x0a = b2f((u16)(rr[tt] & 0xffffu)),     x1a = b2f((u16)(rr[tt] >> 16));
    float x0b = b2f((u16)(rr[tt + 1] & 0xffffu)), x1b = b2f((u16)(rr[tt + 1] >> 16));
    float x0c = b2f((u16)(rr[tt + 2] & 0xffffu)), x1c = b2f((u16)(rr[tt + 2] >> 16));
    float x0d = b2f((u16)(rr[tt + 3] & 0xffffu)), x1d = b2f((u16)(rr[tt + 3] >> 16));
    float a0 = fmaf(wa, x0a, fmaf(wb, x0b, fmaf(wc, x0c, fmaf(wd, x0d, bs0))));
    float a1 = fmaf(wa1, x1a, fmaf(wb1, x1b, fmaf(wc1, x1c, fmaf(wd1, x1d, bs1))));
    float y0 = a0 * sigm(a0), y1 = a1 * sigm(a1);
    if (norm){
      float ss = y0 * y0 + y1 * y1;
      #pragma unroll
      for (int off = 1; off < 64; off <<= 1) ss += __shfl_xor(ss, off);
      float inv = 1.f / fmaxf(sqrtf(ss), 1e-12f);
      y0 *= inv; y1 *= inv;
    }
    u32 r = (u32)f2b(y0) | ((u32)f2b(y1) << 16);
    *(u32*)(outp + ((long)b * CT + t) * ostride + ocol) = r;
  }
}

// ============ chunked delta rule: per-chunk metadata (L=32) ============
__global__ __launch_bounds__(256) void chunk_meta_k(
    const u16* __restrict__ qn, const u16* __restrict__ kn, const u16* __restrict__ vn,
    const float* __restrict__ alpha, const float* __restrict__ beta,
    u16* __restrict__ TGK_g, u16* __restrict__ TVT_g, u16* __restrict__ P_g,
    u16* __restrict__ KTS_g, float* __restrict__ scal_g)
{
  int bid = blockIdx.x;
  int c = bid & 63, bh = bid >> 6;
  int b = bh >> 3, h = bh & 7;
  long rowb = (long)b * CT + c * 32;
  int tid = threadIdx.x, lane = tid & 63, wv = tid >> 6;
  int l15 = lane & 15, lhi = lane >> 4;
  int mt = wv & 1, nt = wv >> 1;

  __shared__ u16 Kc[4096], Qc[4096], Vl[8192];
  __shared__ u16 Vt[10240];    // [v 256][s 32] stride 40
  __shared__ u16 KTG[5120];    // [k 128][s 32] stride 40
  __shared__ u16 TinvL[1280];  // [s 32][s' 32] stride 40
  __shared__ float Al[32 * 33];
  __shared__ float al_s[32], be_s[32], cums[33], bscal[32], gsl[32];

  #pragma unroll
  for (int p = 0; p < 2; p++){
    int X = p * 256 + tid; int r = X >> 4, jj = X & 15;
    gload16(kn + ((rowb + r) * 8 + h) * 128 + (jj ^ (r & 7)) * 8, &Kc[(size_t)X * 8]);
  }
  #pragma unroll
  for (int p = 0; p < 2; p++){
    int X = p * 256 + tid; int r = X >> 4, jj = X & 15;
    gload16(qn + ((rowb + r) * 8 + h) * 128 + (jj ^ (r & 7)) * 8, &Qc[(size_t)X * 8]);
  }
  #pragma unroll
  for (int p = 0; p < 4; p++){
    int X = p * 256 + tid; int r = X >> 5, cc = X & 31;
    gload16(vn + ((rowb + r) * 8 + h) * 256 + cc * 8, &Vl[(size_t)X * 8]);
  }
  if (tid < 32) al_s[tid] = alpha[(rowb + tid) * 8 + h];
  else if (tid < 64) be_s[tid - 32] = beta[(rowb + tid - 32) * 8 + h];
  __syncthreads();
  if (tid == 0){
    float cacc = 0.f; cums[0] = 0.f;
    for (int j = 0; j < 32; j++){ cacc += logf(al_s[j]); cums[j + 1] = cacc; }
  }
  __syncthreads();
  if (tid < 32){
    bscal[tid] = be_s[tid] * expf(cums[32] - cums[tid + 1]);
    gsl[tid] = expf(cums[tid]);
  }
  asm volatile("s_waitcnt vmcnt(0)" ::: "memory");
  __syncthreads();

  #pragma unroll
  for (int i = 0; i < 16; i++){
    u32 lo = Vl[(2 * i) * 256 + tid];
    u32 hi = Vl[(2 * i + 1) * 256 + tid];
    *(u32*)&Vt[tid * 40 + 2 * i] = lo | (hi << 16);
  }

  f32x4 rk = {0.f,0.f,0.f,0.f}, rq = {0.f,0.f,0.f,0.f};
  int ra = mt * 16 + l15, rb = nt * 16 + l15;
  #pragma unroll
  for (int ks = 0; ks < 4; ks++){
    int slot = ks * 4 + lhi;
    bf16x8 ak = *(const bf16x8*)&Kc[ra * 128 + (slot ^ (ra & 7)) * 8];
    bf16x8 aq = *(const bf16x8*)&Qc[ra * 128 + (slot ^ (ra & 7)) * 8];
    bf16x8 bk = *(const bf16x8*)&Kc[rb * 128 + (slot ^ (rb & 7)) * 8];
    rk = __builtin_amdgcn_mfma_f32_16x16x32_bf16(ak, bk, rk, 0, 0, 0);
    rq = __builtin_amdgcn_mfma_f32_16x16x32_bf16(aq, bk, rq, 0, 0, 0);
  }
  int s_ = nt * 16 + l15;
  long pb_ = (long)bid * 1024;
  #pragma unroll
  for (int j = 0; j < 4; j++){
    int i_ = mt * 16 + lhi * 4 + j;
    float e = (s_ < i_) ? expf(cums[i_] - cums[s_ + 1]) * be_s[s_] : 0.f;
    Al[i_ * 33 + s_] = rk[j] * e;
    P_g[pb_ + i_ * 32 + s_] = f2b(rq[j] * e);
  }
  __syncthreads();

  if (tid < 32){
    float x[32];
    #pragma unroll
    for (int i = 0; i < 32; i++) x[i] = (i == tid) ? 1.f : 0.f;
    #pragma unroll
    for (int s = 0; s < 31; s++){
      float xs = x[s];
      #pragma unroll
      for (int i = s + 1; i < 32; i++) x[i] = fmaf(-Al[i * 33 + s], xs, x[i]);
    }
    #pragma unroll
    for (int i = 0; i < 32; i++) TinvL[i * 40 + tid] = f2b(x[i]);
    scal_g[(long)bid * 48 + tid] = gsl[tid];
    if (tid == 0) scal_g[(long)bid * 48 + 32] = expf(cums[32]);
  } else if (tid >= 64){
    int t0 = tid - 64;
    #pragma unroll
    for (int e2 = 0; e2 < 22; e2++){
      int e = t0 + e2 * 192;
      if (e < 4096){
        int k = e >> 5, s2 = e & 31;
        int slot = k >> 3;
        float kv = b2f(Kc[s2 * 128 + (slot ^ (s2 & 7)) * 8 + (k & 7)]);
        KTS_g[(long)bid * 4096 + k * 32 + s2] = f2b(kv * bscal[s2]);
        KTG[k * 40 + s2] = f2b(kv * gsl[s2]);
      }
    }
  }
  __syncthreads();

  long tb = (long)bid * 4096;
  #pragma unroll
  for (int p = 0; p < 4; p++){
    int idx = wv * 4 + p; int ts = idx >> 3, tk = idx & 7;
    bf16x8 aT = *(const bf16x8*)&TinvL[(ts * 16 + l15) * 40 + lhi * 8];
    bf16x8 bK2 = *(const bf16x8*)&KTG[(tk * 16 + l15) * 40 + lhi * 8];
    f32x4 z = {0.f,0.f,0.f,0.f};
    f32x4 d = __builtin_amdgcn_mfma_f32_16x16x32_bf16(aT, bK2, z, 0, 0, 0);
    #pragma unroll
    for (int j = 0; j < 4; j++)
      TGK_g[tb + (ts * 16 + lhi * 4 + j) * 128 + tk * 16 + l15] = f2b(d[j]);
  }
  long vb = (long)bid * 8192;
  #pragma unroll
  for (int p = 0; p < 8; p++){
    int idx = wv * 8 + p; int tv = idx >> 1, ts2 = idx & 1;
    bf16x8 aV = *(const bf16x8*)&Vt[(tv * 16 + l15) * 40 + lhi * 8];
    bf16x8 bT2 = *(const bf16x8*)&TinvL[(ts2 * 16 + l15) * 40 + lhi * 8];
    f32x4 z = {0.f,0.f,0.f,0.f};
    f32x4 d = __builtin_amdgcn_mfma_f32_16x16x32_bf16(aV, bT2, z, 0, 0, 0);
    #pragma unroll
    for (int j = 0; j < 4; j++)
      TVT_g[vb + (tv * 16 + lhi * 4 + j) * 32 + ts2 * 16 + l15] = f2b(d[j]);
  }
}

// ============ chunked delta rule: main scan — EXACT R10 structure (proven) ============
__global__ __launch_bounds__(256) void chunk_scan_k(
    const u16* __restrict__ qn, const u16* __restrict__ TGK_g, const u16* __restrict__ TVT_g,
    const u16* __restrict__ P_g, const u16* __restrict__ KTS_g,
    const float* __restrict__ scal_g, const float* __restrict__ prev,
    u16* __restrict__ obuf, float* __restrict__ fstate)
{
  int bid = blockIdx.x;
  int bh = bid & 31, vs = bid >> 5;
  int b = bh >> 3, h = bh & 7;
  int tid = threadIdx.x, lane = tid & 63, wv = tid >> 6;
  int l15 = lane & 15, lhi = lane >> 4;
  int mv = wv & 1, nn = wv >> 1;

  __shared__ u16 TG[2][4096];
  __shared__ u16 Qc[2][4096];
  __shared__ u16 TVs[2][1024];
  __shared__ float scal[2][48];
  __shared__ u16 KT[2][4096];
  __shared__ u16 Ps[2][1024];
  __shared__ u16 Sb[32 * 136];
  __shared__ u16 Ub[32 * 40];

  auto issue_g1 = [&](int c, int bf){   // 8 loads/wave
    long cb_ = (long)bh * 64 + c;
    const u16* Tb_ = TGK_g + cb_ * 4096;
    #pragma unroll
    for (int p = 0; p < 2; p++){
      int X = p * 256 + tid; int r = X >> 4, jj = X & 15;
      gload16(Tb_ + r * 128 + (jj ^ (r & 7)) * 8, &TG[bf][(size_t)X * 8]);
    }
    long rowb = (long)b * CT + c * 32;
    #pragma unroll
    for (int p = 0; p < 2; p++){
      int X = p * 256 + tid; int r = X >> 4, jj = X & 15;
      gload16(qn + ((rowb + r) * 8 + h) * 128 + (jj ^ (r & 7)) * 8, &Qc[bf][(size_t)X * 8]);
    }
    if (lane < 32){
      int X = wv * 32 + lane; int r = X >> 2, jj = X & 3;
      gload16(TVT_g + cb_ * 8192 + (vs * 32 + r) * 32 + (jj ^ swz3(r)) * 8, &TVs[bf][(size_t)X * 8]);
    }
    long sbase = cb_ * 48;
    #pragma unroll
    for (int p = 0; p < 3; p++){
      int X = wv * 3 + p;
      if (lane == 0) gload16(scal_g + sbase + X * 4, &scal[bf][X * 4]);
    }
  };
  auto issue_g2 = [&](int c, int bf){   // 3 loads/wave
    long cb_ = (long)bh * 64 + c;
    const u16* Kb_ = KTS_g + cb_ * 4096;
    #pragma unroll
    for (int p = 0; p < 2; p++){
      int X = p * 256 + tid; int r = X >> 2, jj = X & 3;
      gload16(Kb_ + (r * 4 + (jj ^ swz3(r))) * 8, &KT[bf][(size_t)X * 8]);
    }
    if (lane < 32){
      int X = wv * 32 + lane; int r = X >> 2, jj = X & 3;
      gload16(P_g + cb_ * 1024 + (r * 4 + (jj ^ swz3(r))) * 8, &Ps[bf][(size_t)X * 8]);
    }
  };

  // ---- prologue: g1(0) then g2(0); prev state -> regs + Sb
  issue_g1(0, 0);
  issue_g2(0, 0);
  f32x4 st[4];
  {
    const float* pbv = prev + ((long)bh * 128) * 256 + vs * 32;
    #pragma unroll
    for (int tt = 0; tt < 4; tt++){
      int k = (nn * 4 + tt) * 16 + l15;
      #pragma unroll
      for (int j = 0; j < 4; j++){
        int v = mv * 16 + lhi * 4 + j;
        st[tt][j] = pbv[(long)k * 256 + v];
      }
    }
  }
  #pragma unroll
  for (int tt = 0; tt < 4; tt++){
    int k = (nn * 4 + tt) * 16 + l15;
    #pragma unroll
    for (int j = 0; j < 4; j++){
      int v = mv * 16 + lhi * 4 + j;
      Sb[v * 136 + k] = f2b(st[tt][j]);
    }
  }
  asm volatile("s_waitcnt vmcnt(3) lgkmcnt(0)" ::: "memory");
  __builtin_amdgcn_s_barrier();

  int rv = mv * 16 + l15, ri = nn * 16 + l15;
  for (int c = 0; c < 64; ++c){
    int bf = c & 1;
    // ---- Phase A: Us = TGK@S, o1 = Q@S; U = TVT - Us -> Ub
    f32x4 us = {0.f,0.f,0.f,0.f}, o1 = {0.f,0.f,0.f,0.f};
    #pragma unroll
    for (int ks = 0; ks < 4; ks++){
      bf16x8 aS = *(const bf16x8*)&Sb[rv * 136 + ks * 32 + lhi * 8];
      int slot = ks * 4 + lhi;
      bf16x8 bT = *(const bf16x8*)&TG[bf][ri * 128 + (slot ^ (ri & 7)) * 8];
      bf16x8 bQ = *(const bf16x8*)&Qc[bf][ri * 128 + (slot ^ (ri & 7)) * 8];
      us = __builtin_amdgcn_mfma_f32_16x16x32_bf16(aS, bT, us, 0, 0, 0);
      o1 = __builtin_amdgcn_mfma_f32_16x16x32_bf16(aS, bQ, o1, 0, 0, 0);
    }
    if (c + 1 < 64) issue_g1(c + 1, bf ^ 1);
    #pragma unroll
    for (int j = 0; j < 4; j++){
      int v = mv * 16 + lhi * 4 + j;
      float tv = b2f(TVs[bf][v * 32 + ((ri >> 3) ^ swz3(v)) * 8 + (ri & 7)]);
      Ub[v * 40 + ri] = f2b(tv - us[j]);
    }
    asm volatile("s_waitcnt lgkmcnt(0)" ::: "memory");
    if (c + 1 < 64) asm volatile("s_waitcnt vmcnt(8)" ::: "memory");
    else            asm volatile("s_waitcnt vmcnt(0)" ::: "memory");
    __builtin_amdgcn_s_barrier();

    // ---- Phase B: O = U@P^T + gi*o1 ; S' = Gt*S + U@KTS^T
    float Gt = scal[bf][32];
    f32x4 oacc;
    {
      bf16x8 aU = *(const bf16x8*)&Ub[rv * 40 + lhi * 8];
      bf16x8 bP = *(const bf16x8*)&Ps[bf][ri * 32 + (lhi ^ swz3(ri)) * 8];
      f32x4 z = {0.f,0.f,0.f,0.f};
      oacc = __builtin_amdgcn_mfma_f32_16x16x32_bf16(aU, bP, z, 0, 0, 0);
      #pragma unroll
      for (int tt = 0; tt < 4; tt++){
        int rk_ = (nn * 4 + tt) * 16 + l15;
        bf16x8 bK = *(const bf16x8*)&KT[bf][rk_ * 32 + (lhi ^ swz3(rk_)) * 8];
        f32x4 ci = st[tt] * Gt;
        st[tt] = __builtin_amdgcn_mfma_f32_16x16x32_bf16(aU, bK, ci, 0, 0, 0);
      }
    }
    {
      float gi = scal[bf][ri];
      ushort4 pk;
      pk.x = f2b(oacc[0] + gi * o1[0]);
      pk.y = f2b(oacc[1] + gi * o1[1]);
      pk.z = f2b(oacc[2] + gi * o1[2]);
      pk.w = f2b(oacc[3] + gi * o1[3]);
      *(ushort4*)&obuf[(((long)bh * CT) + c * 32 + ri) * 256 + vs * 32 + mv * 16 + lhi * 4] = pk;
    }
    if (c + 1 < 64) issue_g2(c + 1, bf ^ 1);
    #pragma unroll
    for (int tt = 0; tt < 4; tt++){
      int k = (nn * 4 + tt) * 16 + l15;
      #pragma unroll
      for (int j = 0; j < 4; j++){
        int v = mv * 16 + lhi * 4 + j;
        Sb[v * 136 + k] = f2b(st[tt][j]);
      }
    }
    asm volatile("s_waitcnt lgkmcnt(0)" ::: "memory");
    if (c + 1 < 64) asm volatile("s_waitcnt vmcnt(3)" ::: "memory");
    else            asm volatile("s_waitcnt vmcnt(0)" ::: "memory");
    __builtin_amdgcn_s_barrier();
  }

  // ---- epilogue: final state
  {
    float* fb = fstate + ((long)bh * 128) * 256 + vs * 32;
    #pragma unroll
    for (int tt = 0; tt < 4; tt++){
      int k = (nn * 4 + tt) * 16 + l15;
      #pragma unroll
      for (int j = 0; j < 4; j++){
        int v = mv * 16 + lhi * 4 + j;
        fb[(long)k * 256 + v] = st[tt][j];
      }
    }
  }
}

// ---------------- gated RMSNorm: one wave per (b,t,h) ----------------
__global__ __launch_bounds__(256) void rms_gate_k(
    const u16* __restrict__ o, const u16* __restrict__ gate,
    const float* __restrict__ nw, u16* __restrict__ ofin)
{
  long idx = (long)blockIdx.x * 4 + (threadIdx.x >> 6);
  int lane = threadIdx.x & 63;
  int h = (int)(idx & 7);
  long bt = idx >> 3;
  int b = (int)(bt >> 11);
  long t = bt & (CT - 1);
  long obase = (((long)(b * 8 + h)) * CT + t) * CDV + lane * 4;
  long base = idx * CDV + lane * 4;
  ushort4 o4 = *(const ushort4*)(o + obase);
  float ox = b2f(o4.x), oy = b2f(o4.y), oz = b2f(o4.z), ow = b2f(o4.w);
  float ss = ox*ox + oy*oy + oz*oz + ow*ow;
  #pragma unroll
  for (int off = 1; off < 64; off <<= 1) ss += __shfl_xor(ss, off);
  float r = rsqrtf(ss * (1.f / CDV) + 1e-5f);
  ushort4 g4 = *(const ushort4*)(gate + base);
  float w0 = nw[lane*4], w1 = nw[lane*4+1], w2 = nw[lane*4+2], w3 = nw[lane*4+3];
  ushort4 res;
  res.x = f2b(ox * r * w0 * sigm(b2f(g4.x)));
  res.y = f2b(oy * r * w1 * sigm(b2f(g4.y)));
  res.z = f2b(oz * r * w2 * sigm(b2f(g4.z)));
  res.w = f2b(ow * r * w3 * sigm(b2f(g4.w)));
  *(ushort4*)(ofin + base) = res;
}

// ---------------- host launch ----------------
extern "C" void kernel_launch(void* const* d_in, const int* in_sizes, int n_in,
                              void* d_out, int out_size, void* d_ws, size_t ws_size,
                              hipStream_t stream)
{
  (void)in_sizes; (void)n_in; (void)out_size; (void)ws_size;
  const float* X    = (const float*)d_in[0];
  const float* prev = (const float*)d_in[1];
  const float* Wq   = (const float*)d_in[2];
  const float* Wk   = (const float*)d_in[3];
  const float* Wv   = (const float*)d_in[4];
  const float* Wa   = (const float*)d_in[5];
  const float* Wb   = (const float*)d_in[6];
  const float* Wg   = (const float*)d_in[7];
  const float* Wo   = (const float*)d_in[8];
  const float* qcw  = (const float*)d_in[9];
  const float* qcb  = (const float*)d_in[10];
  const float* kcw  = (const float*)d_in[11];
  const float* kcb  = (const float*)d_in[12];
  const float* vcw  = (const float*)d_in[13];
  const float* vcb  = (const float*)d_in[14];
  const float* onw  = (const float*)d_in[15];
  const float* Alog = (const float*)d_in[16];
  const float* dtb  = (const float*)d_in[17];

  float* out = (float*)d_out;
  float* fstate = out + (long)CB * CT * CD;

  char* ws = (char*)d_ws;
  size_t off = 0;
  auto alloc = [&](size_t bytes) -> char* {
    char* p = ws + off;
    off += (bytes + 255) & ~(size_t)255;
    return p;
  };
  u16* Xb     = (u16*)alloc(NROW * CD * 2);
  u16* Wqkvt  = (u16*)alloc((size_t)4096 * 1024 * 2);
  u16* Wgt    = (u16*)alloc((size_t)2048 * 1024 * 2);
  u16* Wot    = (u16*)alloc((size_t)1024 * 2048 * 2);
  u16* qkvpre = (u16*)alloc(NROW * 4096 * 2);
  u16* gpre   = (u16*)alloc(NROW * 2048 * 2);
  float* alpha = (float*)alloc(NROW * 8 * 4);
  float* beta  = (float*)alloc(NROW * 8 * 4);
  u16* qn   = (u16*)alloc(NROW * 1024 * 2);
  u16* kn   = (u16*)alloc(NROW * 1024 * 2);
  u16* vn   = (u16*)alloc(NROW * 2048 * 2);
  u16* ofin = (u16*)alloc(NROW * 2048 * 2);
  u16* Wab  = (u16*)alloc((size_t)16 * 1024 * 2);
  // aliases (lifetime-checked):
  // TGK -> Xb (EXACT); TVT -> ofin (EXACT); qkvpre partition:
  //   obuf [0..16,777,216) | P [16,777,216..18,874,368) | scal [18,874,368..19,070,976)
  //   KTS [19,136,512..27,525,120).  Wot never aliased.
  u16* TGK_g  = Xb;
  u16* TVT_g  = ofin;
  u16* obuf   = qkvpre;
  u16* P_g    = qkvpre + (size_t)16777216;
  float* scal_g = (float*)(qkvpre + (size_t)18874368);
  u16* KTS_g  = qkvpre + (size_t)19136512;

  prep_all_k<<<10304, 256, 0, stream>>>(X, Xb, Wa, Wb, Wab,
                                        Wq, Wk, Wv, Wg, Wo, Wqkvt, Wgt, Wot);

  gemm128_k<u16><<<dim3(32, 64), 256, 0, stream>>>(Xb, Wqkvt, qkvpre, 8192, 4096, 1024);
  gemm128_k<u16><<<dim3(16, 64), 256, 0, stream>>>(Xb, Wgt, gpre, 8192, 2048, 1024);
  ab_mfma_k<<<128, 256, 0, stream>>>(Xb, Wab, Alog, dtb, alpha, beta);

  conv_all_k<<<CB * (CT / 8) * CH * 4, 64, 0, stream>>>(qkvpre, qcw, qcb, kcw, kcb, vcw, vcb,
                                                        qn, kn, vn);

  chunk_meta_k<<<2048, 256, 0, stream>>>(qn, kn, vn, alpha, beta,
                                         TGK_g, TVT_g, P_g, KTS_g, scal_g);
  chunk_scan_k<<<256, 256, 0, stream>>>(qn, TGK_g, TVT_g, P_g, KTS_g, scal_g,
                                        prev, obuf, fstate);

  rms_gate_k<<<CB * CT * CH / 4, 256, 0, stream>>>(obuf, gpre, onw, ofin);
  gemm128_k<float><<<dim3(8, 64), 256, 0, stream>>>(ofin, Wot, out, 8192, 1024, 2048);
}